// Round 8
// baseline (277.903 us; speedup 1.0000x reference)
//
#include <hip/hip_runtime.h>
#include <hip/hip_bf16.h>
#include <hip/hip_fp16.h>
#include <math.h>

// GraphEncoderStack: 2x (GCNConv -> BN -> ReLU) + residual + 2 GCN heads + reparam
// N=50000 nodes, E=800000 edges, IN=HIDDEN=128, LATENT=32.
// MFMA f16 GEMM (fp32 accum); fp16 intermediates; padded atomics; fused epilogues.
// Requires n < 65536 (problem fixes n=50000).

#define HID 128
#define LAT 32
#define PSTR 8  // packed[] stride in u64 per node (64B line each -> no false sharing)

typedef _Float16 f16x8 __attribute__((ext_vector_type(8)));
typedef float f32x4 __attribute__((ext_vector_type(4)));

#define LOH(u) __half2float(__ushort_as_half((unsigned short)((u) & 0xFFFFu)))
#define HIH(u) __half2float(__ushort_as_half((unsigned short)((u) >> 16)))

__device__ __forceinline__ unsigned pkh(float a, float b) {
  return (unsigned)__half_as_ushort(__float2half(a)) |
         ((unsigned)__half_as_ushort(__float2half(b)) << 16);
}

// ---------------- degree+count in one padded 64-bit atomic ----------------
// packed[d*PSTR] += (1<<48)|(w*2^24); old>>48 = edge's rank within its dst.

__global__ __launch_bounds__(256) void k_deg_edges(const int* __restrict__ dst,
    const float* __restrict__ w, unsigned long long* __restrict__ packed,
    unsigned short* __restrict__ rank, int E) {
  int e = blockIdx.x * 256 + threadIdx.x;
  if (e < E) {
    int d = dst[e];
    unsigned long long v =
        (1ULL << 48) | (unsigned long long)(w[e] * 16777216.0f);
    unsigned long long old = atomicAdd(&packed[(size_t)d * PSTR], v);
    rank[e] = (unsigned short)(old >> 48);
  }
}

// ---------------- dinv + cnt + per-1024-chunk sum (fused) ----------------
#define SCH 1024

__global__ __launch_bounds__(256) void k_dinv_scan(
    const unsigned long long* __restrict__ packed, float* __restrict__ dinv,
    int* __restrict__ cnt, int* __restrict__ bsum, int n) {
  int t = threadIdx.x;
  int base = blockIdx.x * SCH + t * 4;
  int s = 0;
#pragma unroll
  for (int k = 0; k < 4; ++k) {
    int i = base + k;
    if (i < n) {
      unsigned long long p = packed[(size_t)i * PSTR];
      int c = (int)(p >> 48);
      cnt[i] = c;
      s += c;
      float d = (float)(p & 0xFFFFFFFFFFFFULL) * (1.0f / 16777216.0f) + 1.0f;
      dinv[i] = rsqrtf(d);
    }
  }
#pragma unroll
  for (int off = 32; off; off >>= 1) s += __shfl_down(s, off);
  __shared__ int ws[4];
  if ((t & 63) == 0) ws[t >> 6] = s;
  __syncthreads();
  if (t == 0) bsum[blockIdx.x] = ws[0] + ws[1] + ws[2] + ws[3];
}

__global__ __launch_bounds__(64) void k_scan_mid(const int* __restrict__ bsum,
    int* __restrict__ boff, int* __restrict__ off, int nb, int n) {
  int t = threadIdx.x;
  int val = (t < nb) ? bsum[t] : 0;
  int inc = val;
#pragma unroll
  for (int d = 1; d < 64; d <<= 1) {
    int u = __shfl_up(inc, d);
    if (t >= d) inc += u;
  }
  if (t < nb) boff[t] = inc - val;
  if (t == nb - 1) off[n] = inc;
}

__global__ __launch_bounds__(256) void k_scan_out(const int* __restrict__ cnt,
    const int* __restrict__ boff, int* __restrict__ off, int n) {
  int base = blockIdx.x * SCH + threadIdx.x * 4;
  int4 v = make_int4(0, 0, 0, 0);
  if (base + 3 < n) v = *(const int4*)&cnt[base];
  else {
    if (base + 0 < n) v.x = cnt[base + 0];
    if (base + 1 < n) v.y = cnt[base + 1];
    if (base + 2 < n) v.z = cnt[base + 2];
  }
  int s = v.x + v.y + v.z + v.w;
  int lane = threadIdx.x & 63, wv = threadIdx.x >> 6;
  int inc = s;
#pragma unroll
  for (int d = 1; d < 64; d <<= 1) {
    int u = __shfl_up(inc, d);
    if (lane >= d) inc += u;
  }
  __shared__ int wsum[4];
  if (lane == 63) wsum[wv] = inc;
  __syncthreads();
  int wbase = 0;
  for (int i = 0; i < wv; ++i) wbase += wsum[i];
  int ex = boff[blockIdx.x] + wbase + inc - s;
  int4 o = make_int4(ex, ex + v.x, ex + v.x + v.y, ex + v.x + v.y + v.z);
  if (base + 3 < n) {
    *(int4*)&off[base] = o;
  } else {
    if (base + 0 < n) off[base + 0] = o.x;
    if (base + 1 < n) off[base + 1] = o.y;
    if (base + 2 < n) off[base + 2] = o.z;
  }
}

// CSR record: 4B = (src << 16) | fp16(w * dinv[src]); pos = coff[dst]+rank.
__global__ __launch_bounds__(256) void k_fill(const int* __restrict__ src,
    const int* __restrict__ dst, const float* __restrict__ w,
    const float* __restrict__ dinv, const int* __restrict__ coff,
    const unsigned short* __restrict__ rank, unsigned int* __restrict__ erec,
    int E) {
  int e = blockIdx.x * 256 + threadIdx.x;
  if (e < E) {
    int s = src[e], d = dst[e];
    int p = coff[d] + (int)rank[e];
    __half u = __float2half(w[e] * dinv[s]);
    erec[p] = ((unsigned)s << 16) | (unsigned)__half_as_ushort(u);
  }
}

// ---------------- W pre-swizzle into MFMA fragment order (fp16) ----------
template <int NOUT>
__global__ __launch_bounds__(256) void k_wprep(const float* __restrict__ W,
    uint4* __restrict__ Wsw) {
  int tid = blockIdx.x * 256 + threadIdx.x;
  if (tid >= (NOUT / 16) * 4 * 64) return;
  int l = tid & 63, ks = (tid >> 6) & 3, nt = tid >> 8;
  int col = nt * 16 + (l & 15);
  int kbase = ks * 32 + (l >> 4) * 8;
  _Float16 vals[8];
#pragma unroll
  for (int i = 0; i < 8; ++i) vals[i] = (_Float16)W[(kbase + i) * NOUT + col];
  Wsw[tid] = *(uint4*)vals;
}

// head weights: concat [Wm|Ws] virtually, swizzle for NOUT=64; also bcat.
__global__ __launch_bounds__(256) void k_wprepc(const float* __restrict__ Wm,
    const float* __restrict__ Ws, const float* __restrict__ bm,
    const float* __restrict__ bs, uint4* __restrict__ Wsw,
    float* __restrict__ bcat) {
  int tid = blockIdx.x * 256 + threadIdx.x;
  if (tid < 64) bcat[tid] = (tid < 32) ? bm[tid] : bs[tid - 32];
  if (tid >= 4 * 4 * 64) return;
  int l = tid & 63, ks = (tid >> 6) & 3, nt = tid >> 8;
  int col = nt * 16 + (l & 15);
  int kbase = ks * 32 + (l >> 4) * 8;
  const float* Wsrc = (col < 32) ? Wm : Ws;
  int c = (col < 32) ? col : col - 32;
  _Float16 vals[8];
#pragma unroll
  for (int i = 0; i < 8; ++i) vals[i] = (_Float16)Wsrc[(kbase + i) * 32 + c];
  Wsw[tid] = *(uint4*)vals;
}

// ---------------- MFMA GEMM: [n,128] x [128,NOUT] -> fp16 Y --------------
// BM=64 rows/block, 4 waves; wave owns 16 rows x NOUT cols.
// MODE 0: fp32 X plain. MODE 1: fp16 X, BN(from stats,g,be)+relu, residual
// side-write. MODE 2: fp16 X, BN+relu+residual add.

#define BM 64
template <int NOUT, int MODE>
__global__ __launch_bounds__(256) void k_gemm(const void* __restrict__ Xv,
    const uint4* __restrict__ Wsw, unsigned short* __restrict__ Y, int n,
    const float* __restrict__ stats, const float* __restrict__ g,
    const float* __restrict__ be, const uint4* __restrict__ Rres,
    uint4* __restrict__ Rout) {
  constexpr int NT = NOUT / 16;
  __shared__ _Float16 xs[BM * 128];
  __shared__ float scsh[256];
  const int t = threadIdx.x;
  const int row0 = blockIdx.x * BM;
  if (MODE >= 1) {
    if (t < 128) {
      float m = stats[t] / (float)n;
      float var = fmaxf(stats[128 + t] / (float)n - m * m, 0.f);
      float sc = g[t] * rsqrtf(var + 1e-5f);
      scsh[t] = sc;
      scsh[128 + t] = be[t] - m * sc;
    }
    __syncthreads();
  }
  for (int i = t; i < BM * 16; i += 256) {
    int r = i >> 4, cg = i & 15;
    bool valid = (row0 + r) < n;
    float f[8];
    if (MODE == 0) {
      float4 v0 = make_float4(0.f, 0.f, 0.f, 0.f), v1 = v0;
      if (valid) {
        v0 = ((const float4*)Xv)[(size_t)(row0 + r) * 32 + cg * 2];
        v1 = ((const float4*)Xv)[(size_t)(row0 + r) * 32 + cg * 2 + 1];
      }
      f[0] = v0.x; f[1] = v0.y; f[2] = v0.z; f[3] = v0.w;
      f[4] = v1.x; f[5] = v1.y; f[6] = v1.z; f[7] = v1.w;
    } else {
      uint4 h = valid ? ((const uint4*)Xv)[(size_t)(row0 + r) * 16 + cg]
                      : make_uint4(0, 0, 0, 0);
      f[0] = LOH(h.x); f[1] = HIH(h.x); f[2] = LOH(h.y); f[3] = HIH(h.y);
      f[4] = LOH(h.z); f[5] = HIH(h.z); f[6] = LOH(h.w); f[7] = HIH(h.w);
    }
    if (MODE >= 1) {
      int c0 = cg * 8;
#pragma unroll
      for (int j = 0; j < 8; ++j)
        f[j] = fmaxf(f[j] * scsh[c0 + j] + scsh[128 + c0 + j], 0.f);
      if (MODE == 2 && valid) {
        uint4 rr = Rres[(size_t)(row0 + r) * 16 + cg];
        f[0] += LOH(rr.x); f[1] += HIH(rr.x);
        f[2] += LOH(rr.y); f[3] += HIH(rr.y);
        f[4] += LOH(rr.z); f[5] += HIH(rr.z);
        f[6] += LOH(rr.w); f[7] += HIH(rr.w);
      }
    }
    uint4 pk;
    pk.x = pkh(f[0], f[1]);
    pk.y = pkh(f[2], f[3]);
    pk.z = pkh(f[4], f[5]);
    pk.w = pkh(f[6], f[7]);
    if (MODE == 1 && valid) Rout[(size_t)(row0 + r) * 16 + cg] = pk;
    *(uint4*)&xs[r * 128 + ((cg ^ (r & 15)) << 3)] = pk;
  }
  __syncthreads();

  const int lane = t & 63;
  const int wave = t >> 6;
  const int arow = wave * 16 + (lane & 15);
  f16x8 a[4];
#pragma unroll
  for (int ks = 0; ks < 4; ++ks) {
    int cg = ks * 4 + (lane >> 4);
    a[ks] = *(const f16x8*)&xs[arow * 128 + ((cg ^ (arow & 15)) << 3)];
  }
  const f16x8* Wf = (const f16x8*)Wsw;
  f32x4 acc[NT];
#pragma unroll
  for (int nt = 0; nt < NT; ++nt) acc[nt] = (f32x4)(0.f);
#pragma unroll
  for (int nt = 0; nt < NT; ++nt) {
#pragma unroll
    for (int ks = 0; ks < 4; ++ks) {
      f16x8 b = Wf[(nt * 4 + ks) * 64 + lane];
      acc[nt] = __builtin_amdgcn_mfma_f32_16x16x32_f16(a[ks], b, acc[nt], 0, 0, 0);
    }
  }
  const int rbase = row0 + wave * 16 + (lane >> 4) * 4;
  const int cbase = lane & 15;
#pragma unroll
  for (int j = 0; j < 4; ++j) {
    int row = rbase + j;
    if (row < n) {
#pragma unroll
      for (int nt = 0; nt < NT; ++nt)
        Y[(size_t)row * NOUT + nt * 16 + cbase] =
            __half_as_ushort(__float2half(acc[nt][j]));
    }
  }
}

// ------------- CSR propagation over fp16 rows, F=128, fp16 out ----------
// out[d] = di * (sum_e u_e*T[src_e] + di*T[d]) + bias,  di = dinv[d].
__global__ __launch_bounds__(256) void k_propb128(const uint4* __restrict__ T,
    const float* __restrict__ dinv, const int* __restrict__ off,
    const unsigned int* __restrict__ erec, const float* __restrict__ bias,
    uint4* __restrict__ outv, int n) {
  constexpr int TPN = 16;
  int node = blockIdx.x * 16 + threadIdx.x / TPN;
  int f8 = threadIdx.x % TPN;
  if (node >= n) return;
  float di = dinv[node];
  float acc[8];
  {
    uint4 v = T[(size_t)node * TPN + f8];
    acc[0] = di * LOH(v.x); acc[1] = di * HIH(v.x);
    acc[2] = di * LOH(v.y); acc[3] = di * HIH(v.y);
    acc[4] = di * LOH(v.z); acc[5] = di * HIH(v.z);
    acc[6] = di * LOH(v.w); acc[7] = di * HIH(v.w);
  }
  int e = off[node], eend = off[node + 1];
  for (; e + 1 < eend; e += 2) {
    unsigned r0 = erec[e], r1 = erec[e + 1];
    uint4 v0 = T[(size_t)(r0 >> 16) * TPN + f8];
    uint4 v1 = T[(size_t)(r1 >> 16) * TPN + f8];
    float n0 = LOH(r0), n1 = LOH(r1);
    acc[0] = fmaf(n0, LOH(v0.x), acc[0]); acc[1] = fmaf(n0, HIH(v0.x), acc[1]);
    acc[2] = fmaf(n0, LOH(v0.y), acc[2]); acc[3] = fmaf(n0, HIH(v0.y), acc[3]);
    acc[4] = fmaf(n0, LOH(v0.z), acc[4]); acc[5] = fmaf(n0, HIH(v0.z), acc[5]);
    acc[6] = fmaf(n0, LOH(v0.w), acc[6]); acc[7] = fmaf(n0, HIH(v0.w), acc[7]);
    acc[0] = fmaf(n1, LOH(v1.x), acc[0]); acc[1] = fmaf(n1, HIH(v1.x), acc[1]);
    acc[2] = fmaf(n1, LOH(v1.y), acc[2]); acc[3] = fmaf(n1, HIH(v1.y), acc[3]);
    acc[4] = fmaf(n1, LOH(v1.z), acc[4]); acc[5] = fmaf(n1, HIH(v1.z), acc[5]);
    acc[6] = fmaf(n1, LOH(v1.w), acc[6]); acc[7] = fmaf(n1, HIH(v1.w), acc[7]);
  }
  if (e < eend) {
    unsigned r0 = erec[e];
    uint4 v0 = T[(size_t)(r0 >> 16) * TPN + f8];
    float n0 = LOH(r0);
    acc[0] = fmaf(n0, LOH(v0.x), acc[0]); acc[1] = fmaf(n0, HIH(v0.x), acc[1]);
    acc[2] = fmaf(n0, LOH(v0.y), acc[2]); acc[3] = fmaf(n0, HIH(v0.y), acc[3]);
    acc[4] = fmaf(n0, LOH(v0.z), acc[4]); acc[5] = fmaf(n0, HIH(v0.z), acc[5]);
    acc[6] = fmaf(n0, LOH(v0.w), acc[6]); acc[7] = fmaf(n0, HIH(v0.w), acc[7]);
  }
  float4 b0 = *(const float4*)&bias[f8 * 8];
  float4 b1 = *(const float4*)&bias[f8 * 8 + 4];
  uint4 pk;
  pk.x = pkh(fmaf(di, acc[0], b0.x), fmaf(di, acc[1], b0.y));
  pk.y = pkh(fmaf(di, acc[2], b0.z), fmaf(di, acc[3], b0.w));
  pk.z = pkh(fmaf(di, acc[4], b1.x), fmaf(di, acc[5], b1.y));
  pk.w = pkh(fmaf(di, acc[6], b1.z), fmaf(di, acc[7], b1.w));
  outv[(size_t)node * TPN + f8] = pk;
}

// ------------- heads prop (F=64) fused with reparameterization ----------
// cols 0..31 = q_m, 32..63 = q_s. Thread f8<4 holds qm[8], partner f8+4
// holds qs[8] for the same latent j range; exchange via shfl_xor(4).
__global__ __launch_bounds__(256) void k_prop64_final(const uint4* __restrict__ T,
    const float* __restrict__ dinv, const int* __restrict__ off,
    const unsigned int* __restrict__ erec, const float* __restrict__ bias,
    const float* __restrict__ eps, float* __restrict__ out, int n) {
  constexpr int TPN = 8;
  int node = blockIdx.x * 32 + threadIdx.x / TPN;
  int f8 = threadIdx.x % TPN;
  if (node >= n) return;
  float di = dinv[node];
  float acc[8];
  {
    uint4 v = T[(size_t)node * TPN + f8];
    acc[0] = di * LOH(v.x); acc[1] = di * HIH(v.x);
    acc[2] = di * LOH(v.y); acc[3] = di * HIH(v.y);
    acc[4] = di * LOH(v.z); acc[5] = di * HIH(v.z);
    acc[6] = di * LOH(v.w); acc[7] = di * HIH(v.w);
  }
  int e = off[node], eend = off[node + 1];
  for (; e + 1 < eend; e += 2) {
    unsigned r0 = erec[e], r1 = erec[e + 1];
    uint4 v0 = T[(size_t)(r0 >> 16) * TPN + f8];
    uint4 v1 = T[(size_t)(r1 >> 16) * TPN + f8];
    float n0 = LOH(r0), n1 = LOH(r1);
    acc[0] = fmaf(n0, LOH(v0.x), acc[0]); acc[1] = fmaf(n0, HIH(v0.x), acc[1]);
    acc[2] = fmaf(n0, LOH(v0.y), acc[2]); acc[3] = fmaf(n0, HIH(v0.y), acc[3]);
    acc[4] = fmaf(n0, LOH(v0.z), acc[4]); acc[5] = fmaf(n0, HIH(v0.z), acc[5]);
    acc[6] = fmaf(n0, LOH(v0.w), acc[6]); acc[7] = fmaf(n0, HIH(v0.w), acc[7]);
    acc[0] = fmaf(n1, LOH(v1.x), acc[0]); acc[1] = fmaf(n1, HIH(v1.x), acc[1]);
    acc[2] = fmaf(n1, LOH(v1.y), acc[2]); acc[3] = fmaf(n1, HIH(v1.y), acc[3]);
    acc[4] = fmaf(n1, LOH(v1.z), acc[4]); acc[5] = fmaf(n1, HIH(v1.z), acc[5]);
    acc[6] = fmaf(n1, LOH(v1.w), acc[6]); acc[7] = fmaf(n1, HIH(v1.w), acc[7]);
  }
  if (e < eend) {
    unsigned r0 = erec[e];
    uint4 v0 = T[(size_t)(r0 >> 16) * TPN + f8];
    float n0 = LOH(r0);
    acc[0] = fmaf(n0, LOH(v0.x), acc[0]); acc[1] = fmaf(n0, HIH(v0.x), acc[1]);
    acc[2] = fmaf(n0, LOH(v0.y), acc[2]); acc[3] = fmaf(n0, HIH(v0.y), acc[3]);
    acc[4] = fmaf(n0, LOH(v0.z), acc[4]); acc[5] = fmaf(n0, HIH(v0.z), acc[5]);
    acc[6] = fmaf(n0, LOH(v0.w), acc[6]); acc[7] = fmaf(n0, HIH(v0.w), acc[7]);
  }
  float4 b0 = *(const float4*)&bias[f8 * 8];
  float4 b1 = *(const float4*)&bias[f8 * 8 + 4];
  float r[8];
  r[0] = fmaf(di, acc[0], b0.x); r[1] = fmaf(di, acc[1], b0.y);
  r[2] = fmaf(di, acc[2], b0.z); r[3] = fmaf(di, acc[3], b0.w);
  r[4] = fmaf(di, acc[4], b1.x); r[5] = fmaf(di, acc[5], b1.y);
  r[6] = fmaf(di, acc[6], b1.z); r[7] = fmaf(di, acc[7], b1.w);
  // exchange with partner lane (^4): f8<4 gets qs, f8>=4 gets qm (unused)
  float p[8];
#pragma unroll
  for (int i = 0; i < 8; ++i) p[i] = __shfl_xor(r[i], 4);
  size_t M = (size_t)n * 32;
  if (f8 < 4) {
    int jb = f8 * 8;
    float4 e0 = *(const float4*)&eps[(size_t)node * 32 + jb];
    float4 e1 = *(const float4*)&eps[(size_t)node * 32 + jb + 4];
    float ev[8] = {e0.x, e0.y, e0.z, e0.w, e1.x, e1.y, e1.z, e1.w};
    float qz[8];
#pragma unroll
    for (int i = 0; i < 8; ++i) {
      float qs = p[i];
      float sp = fmaxf(qs, 0.f) + log1pf(expf(-fabsf(qs)));
      qz[i] = fmaf(sp + 1e-6f, ev[i], r[i]);
    }
    float* oz = &out[(size_t)node * 32 + jb];
    *(float4*)oz = make_float4(qz[0], qz[1], qz[2], qz[3]);
    *(float4*)(oz + 4) = make_float4(qz[4], qz[5], qz[6], qz[7]);
    float* om = &out[M + (size_t)node * 32 + jb];
    *(float4*)om = make_float4(r[0], r[1], r[2], r[3]);
    *(float4*)(om + 4) = make_float4(r[4], r[5], r[6], r[7]);
  } else {
    int jb = (f8 - 4) * 8;
    float* os = &out[2 * M + (size_t)node * 32 + jb];
    *(float4*)os = make_float4(r[0], r[1], r[2], r[3]);
    *(float4*)(os + 4) = make_float4(r[4], r[5], r[6], r[7]);
  }
}

// ---------------- BatchNorm stats over fp16 matrix ----------------

__global__ __launch_bounds__(128) void k_stats(
    const unsigned short* __restrict__ X, float* __restrict__ stats, int n) {
  int col = threadIdx.x;
  float s = 0.f, s2 = 0.f;
  for (int r = blockIdx.x; r < n; r += gridDim.x) {
    float v = __half2float(__ushort_as_half(X[(size_t)r * 128 + col]));
    s += v; s2 += v * v;
  }
  atomicAdd(&stats[col], s);
  atomicAdd(&stats[128 + col], s2);
}

// ---------------- launch ----------------

extern "C" void kernel_launch(void* const* d_in, const int* in_sizes, int n_in,
                              void* d_out, int out_size, void* d_ws, size_t ws_size,
                              hipStream_t stream) {
  const float* x  = (const float*)d_in[0];
  const int*   ei = (const int*)d_in[1];
  const float* ew = (const float*)d_in[2];
  const float* W0 = (const float*)d_in[3];
  const float* b0 = (const float*)d_in[4];
  const float* W1 = (const float*)d_in[5];
  const float* b1 = (const float*)d_in[6];
  const float* g0 = (const float*)d_in[7];
  const float* be0 = (const float*)d_in[8];
  const float* g1 = (const float*)d_in[9];
  const float* be1 = (const float*)d_in[10];
  const float* Wm = (const float*)d_in[11];
  const float* bm = (const float*)d_in[12];
  const float* Ws = (const float*)d_in[13];
  const float* bs = (const float*)d_in[14];
  const float* eps = (const float*)d_in[15];
  float* out = (float*)d_out;

  const int n = in_sizes[0] / HID;
  const int E = in_sizes[1] / 2;
  const int* esrc = ei;
  const int* edst = ei + E;

  char* base = (char*)d_ws;
  size_t cur = 0;
  auto alloc = [&](size_t bytes) {
    size_t o = cur;
    cur = (cur + bytes + 255) & ~(size_t)255;
    return (void*)(base + o);
  };
  unsigned long long* packed = (unsigned long long*)alloc((size_t)n * PSTR * 8);
  float* dinv  = (float*)alloc((size_t)n * 4);
  int*   cnt   = (int*)alloc((size_t)n * 4);
  int*   coff  = (int*)alloc((size_t)(n + 1) * 4);
  unsigned short* rank = (unsigned short*)alloc((size_t)E * 2);
  unsigned int* erec = (unsigned int*)alloc((size_t)E * 4);
  int*   bsum  = (int*)alloc(64 * 4);
  int*   boff  = (int*)alloc(64 * 4);
  float* stats0 = (float*)alloc(256 * 4);
  float* stats1 = (float*)alloc(256 * 4);
  float* bcat  = (float*)alloc(64 * 4);
  uint4* Wsw0  = (uint4*)alloc(8 * 4 * 64 * 16);
  uint4* Wsw1  = (uint4*)alloc(8 * 4 * 64 * 16);
  uint4* Wswc  = (uint4*)alloc(4 * 4 * 64 * 16);
  unsigned short* bufA = (unsigned short*)alloc((size_t)n * 128 * 2);  // fp16
  unsigned short* bufB = (unsigned short*)alloc((size_t)n * 128 * 2);  // fp16
  unsigned short* bufC = (unsigned short*)alloc((size_t)n * 128 * 2);  // fp16 residual
  (void)ws_size;

  const int eb = (E + 255) / 256;
  const int gemmb = (n + BM - 1) / BM;
  const int scb = (n + SCH - 1) / SCH;

  // --- norm + CSR ---
  hipMemsetAsync(packed, 0, (size_t)n * PSTR * 8, stream);
  hipMemsetAsync(stats0, 0, 256 * 4, stream);
  hipMemsetAsync(stats1, 0, 256 * 4, stream);
  k_deg_edges<<<eb, 256, 0, stream>>>(edst, ew, packed, rank, E);
  k_dinv_scan<<<scb, 256, 0, stream>>>(packed, dinv, cnt, bsum, n);
  k_scan_mid<<<1, 64, 0, stream>>>(bsum, boff, coff, scb, n);
  k_scan_out<<<scb, 256, 0, stream>>>(cnt, boff, coff, n);
  k_fill<<<eb, 256, 0, stream>>>(esrc, edst, ew, dinv, coff, rank, erec, E);
  k_wprep<128><<<8, 256, 0, stream>>>(W0, Wsw0);
  k_wprep<128><<<8, 256, 0, stream>>>(W1, Wsw1);
  k_wprepc<<<4, 256, 0, stream>>>(Wm, Ws, bm, bs, Wswc, bcat);

  // --- layer 0 ---
  k_gemm<128, 0><<<gemmb, 256, 0, stream>>>(x, Wsw0, bufA, n, nullptr, nullptr,
                                            nullptr, nullptr, nullptr);
  k_propb128<<<(n + 15) / 16, 256, 0, stream>>>((const uint4*)bufA, dinv, coff,
                                                erec, b0, (uint4*)bufB, n);
  k_stats<<<512, 128, 0, stream>>>(bufB, stats0, n);

  // --- layer 1 (BN0+relu in gemm staging; residual h0 -> bufC fp16) ---
  k_gemm<128, 1><<<gemmb, 256, 0, stream>>>(bufB, Wsw1, bufA, n, stats0, g0, be0,
                                            nullptr, (uint4*)bufC);
  k_propb128<<<(n + 15) / 16, 256, 0, stream>>>((const uint4*)bufA, dinv, coff,
                                                erec, b1, (uint4*)bufB, n);
  k_stats<<<512, 128, 0, stream>>>(bufB, stats1, n);

  // --- heads (BN1+relu+residual in gemm staging; mean||logstd) ---
  k_gemm<64, 2><<<gemmb, 256, 0, stream>>>(bufB, Wswc, bufA, n, stats1, g1, be1,
                                           (const uint4*)bufC, nullptr);
  k_prop64_final<<<(n + 31) / 32, 256, 0, stream>>>((const uint4*)bufA, dinv,
                                                    coff, erec, bcat, eps, out, n);
}

// Round 9
// 230.777 us; speedup vs baseline: 1.2042x; 1.2042x over previous
//
#include <hip/hip_runtime.h>
#include <hip/hip_bf16.h>
#include <hip/hip_fp16.h>
#include <math.h>

// GraphEncoderStack: 2x (GCNConv -> BN -> ReLU) + residual + 2 GCN heads + reparam
// N=50000 nodes, E=800000 edges, IN=HIDDEN=128, LATENT=32.
// MFMA f16 GEMM (fp32 accum); fp16 intermediates; fused epilogues.
// Requires n < 65536 (problem fixes n=50000).

#define HID 128
#define LAT 32

typedef _Float16 f16x8 __attribute__((ext_vector_type(8)));
typedef float f32x4 __attribute__((ext_vector_type(4)));

#define LOH(u) __half2float(__ushort_as_half((unsigned short)((u) & 0xFFFFu)))
#define HIH(u) __half2float(__ushort_as_half((unsigned short)((u) >> 16)))

__device__ __forceinline__ unsigned pkh(float a, float b) {
  return (unsigned)__half_as_ushort(__float2half(a)) |
         ((unsigned)__half_as_ushort(__float2half(b)) << 16);
}

// ---------------- degree+count in one packed 64-bit atomic ----------------
// packed[d] += (1<<48)|(w*2^24); old>>48 = edge's rank within its dst.
// PSTR=1: 400KB footprint, L2-resident (R8 showed padding doesn't help:
// atomics execute memory-side; cost ~ op count + line fetches).

__global__ __launch_bounds__(256) void k_deg_edges(const int* __restrict__ dst,
    const float* __restrict__ w, unsigned long long* __restrict__ packed,
    unsigned short* __restrict__ rank, int E) {
  int e = blockIdx.x * 256 + threadIdx.x;
  if (e < E) {
    int d = dst[e];
    unsigned long long v =
        (1ULL << 48) | (unsigned long long)(w[e] * 16777216.0f);
    unsigned long long old = atomicAdd(&packed[d], v);
    rank[e] = (unsigned short)(old >> 48);
  }
}

// ---------------- dinv + cnt + per-1024-chunk sum (fused) ----------------
#define SCH 1024

__global__ __launch_bounds__(256) void k_dinv_scan(
    const unsigned long long* __restrict__ packed, float* __restrict__ dinv,
    int* __restrict__ cnt, int* __restrict__ bsum, int n) {
  int t = threadIdx.x;
  int base = blockIdx.x * SCH + t * 4;
  int s = 0;
#pragma unroll
  for (int k = 0; k < 4; ++k) {
    int i = base + k;
    if (i < n) {
      unsigned long long p = packed[i];
      int c = (int)(p >> 48);
      cnt[i] = c;
      s += c;
      float d = (float)(p & 0xFFFFFFFFFFFFULL) * (1.0f / 16777216.0f) + 1.0f;
      dinv[i] = rsqrtf(d);
    }
  }
#pragma unroll
  for (int off = 32; off; off >>= 1) s += __shfl_down(s, off);
  __shared__ int ws[4];
  if ((t & 63) == 0) ws[t >> 6] = s;
  __syncthreads();
  if (t == 0) bsum[blockIdx.x] = ws[0] + ws[1] + ws[2] + ws[3];
}

__global__ __launch_bounds__(64) void k_scan_mid(const int* __restrict__ bsum,
    int* __restrict__ boff, int* __restrict__ off, int nb, int n) {
  int t = threadIdx.x;
  int val = (t < nb) ? bsum[t] : 0;
  int inc = val;
#pragma unroll
  for (int d = 1; d < 64; d <<= 1) {
    int u = __shfl_up(inc, d);
    if (t >= d) inc += u;
  }
  if (t < nb) boff[t] = inc - val;
  if (t == nb - 1) off[n] = inc;
}

__global__ __launch_bounds__(256) void k_scan_out(const int* __restrict__ cnt,
    const int* __restrict__ boff, int* __restrict__ off, int n) {
  int base = blockIdx.x * SCH + threadIdx.x * 4;
  int4 v = make_int4(0, 0, 0, 0);
  if (base + 3 < n) v = *(const int4*)&cnt[base];
  else {
    if (base + 0 < n) v.x = cnt[base + 0];
    if (base + 1 < n) v.y = cnt[base + 1];
    if (base + 2 < n) v.z = cnt[base + 2];
  }
  int s = v.x + v.y + v.z + v.w;
  int lane = threadIdx.x & 63, wv = threadIdx.x >> 6;
  int inc = s;
#pragma unroll
  for (int d = 1; d < 64; d <<= 1) {
    int u = __shfl_up(inc, d);
    if (lane >= d) inc += u;
  }
  __shared__ int wsum[4];
  if (lane == 63) wsum[wv] = inc;
  __syncthreads();
  int wbase = 0;
  for (int i = 0; i < wv; ++i) wbase += wsum[i];
  int ex = boff[blockIdx.x] + wbase + inc - s;
  int4 o = make_int4(ex, ex + v.x, ex + v.x + v.y, ex + v.x + v.y + v.z);
  if (base + 3 < n) {
    *(int4*)&off[base] = o;
  } else {
    if (base + 0 < n) off[base + 0] = o.x;
    if (base + 1 < n) off[base + 1] = o.y;
    if (base + 2 < n) off[base + 2] = o.z;
  }
}

// CSR record: 4B = (src << 16) | fp16(w * dinv[src]); pos = coff[dst]+rank.
__global__ __launch_bounds__(256) void k_fill(const int* __restrict__ src,
    const int* __restrict__ dst, const float* __restrict__ w,
    const float* __restrict__ dinv, const int* __restrict__ coff,
    const unsigned short* __restrict__ rank, unsigned int* __restrict__ erec,
    int E) {
  int e = blockIdx.x * 256 + threadIdx.x;
  if (e < E) {
    int s = src[e], d = dst[e];
    int p = coff[d] + (int)rank[e];
    __half u = __float2half(w[e] * dinv[s]);
    erec[p] = ((unsigned)s << 16) | (unsigned)__half_as_ushort(u);
  }
}

// ---------------- W pre-swizzle into MFMA fragment order (fp16) ----------
template <int NOUT>
__global__ __launch_bounds__(256) void k_wprep(const float* __restrict__ W,
    uint4* __restrict__ Wsw) {
  int tid = blockIdx.x * 256 + threadIdx.x;
  if (tid >= (NOUT / 16) * 4 * 64) return;
  int l = tid & 63, ks = (tid >> 6) & 3, nt = tid >> 8;
  int col = nt * 16 + (l & 15);
  int kbase = ks * 32 + (l >> 4) * 8;
  _Float16 vals[8];
#pragma unroll
  for (int i = 0; i < 8; ++i) vals[i] = (_Float16)W[(kbase + i) * NOUT + col];
  Wsw[tid] = *(uint4*)vals;
}

// head weights: concat [Wm|Ws] virtually, swizzle for NOUT=64; also bcat.
__global__ __launch_bounds__(256) void k_wprepc(const float* __restrict__ Wm,
    const float* __restrict__ Ws, const float* __restrict__ bm,
    const float* __restrict__ bs, uint4* __restrict__ Wsw,
    float* __restrict__ bcat) {
  int tid = blockIdx.x * 256 + threadIdx.x;
  if (tid < 64) bcat[tid] = (tid < 32) ? bm[tid] : bs[tid - 32];
  if (tid >= 4 * 4 * 64) return;
  int l = tid & 63, ks = (tid >> 6) & 3, nt = tid >> 8;
  int col = nt * 16 + (l & 15);
  int kbase = ks * 32 + (l >> 4) * 8;
  const float* Wsrc = (col < 32) ? Wm : Ws;
  int c = (col < 32) ? col : col - 32;
  _Float16 vals[8];
#pragma unroll
  for (int i = 0; i < 8; ++i) vals[i] = (_Float16)Wsrc[(kbase + i) * 32 + c];
  Wsw[tid] = *(uint4*)vals;
}

// ---------------- MFMA GEMM: [n,128] x [128,NOUT] -> fp16 Y --------------
// BM=64 rows/block, 4 waves; wave owns 16 rows x NOUT cols.
// MODE 0: fp32 X plain. MODE 1: fp16 X, BN(from stats,g,be)+relu, residual
// side-write. MODE 2: fp16 X, BN+relu+residual add.

#define BM 64
template <int NOUT, int MODE>
__global__ __launch_bounds__(256) void k_gemm(const void* __restrict__ Xv,
    const uint4* __restrict__ Wsw, unsigned short* __restrict__ Y, int n,
    const float* __restrict__ stats, const float* __restrict__ g,
    const float* __restrict__ be, const uint4* __restrict__ Rres,
    uint4* __restrict__ Rout) {
  constexpr int NT = NOUT / 16;
  __shared__ _Float16 xs[BM * 128];
  __shared__ float scsh[256];
  const int t = threadIdx.x;
  const int row0 = blockIdx.x * BM;
  if (MODE >= 1) {
    if (t < 128) {
      float m = stats[t] / (float)n;
      float var = fmaxf(stats[128 + t] / (float)n - m * m, 0.f);
      float sc = g[t] * rsqrtf(var + 1e-5f);
      scsh[t] = sc;
      scsh[128 + t] = be[t] - m * sc;
    }
    __syncthreads();
  }
  for (int i = t; i < BM * 16; i += 256) {
    int r = i >> 4, cg = i & 15;
    bool valid = (row0 + r) < n;
    float f[8];
    if (MODE == 0) {
      float4 v0 = make_float4(0.f, 0.f, 0.f, 0.f), v1 = v0;
      if (valid) {
        v0 = ((const float4*)Xv)[(size_t)(row0 + r) * 32 + cg * 2];
        v1 = ((const float4*)Xv)[(size_t)(row0 + r) * 32 + cg * 2 + 1];
      }
      f[0] = v0.x; f[1] = v0.y; f[2] = v0.z; f[3] = v0.w;
      f[4] = v1.x; f[5] = v1.y; f[6] = v1.z; f[7] = v1.w;
    } else {
      uint4 h = valid ? ((const uint4*)Xv)[(size_t)(row0 + r) * 16 + cg]
                      : make_uint4(0, 0, 0, 0);
      f[0] = LOH(h.x); f[1] = HIH(h.x); f[2] = LOH(h.y); f[3] = HIH(h.y);
      f[4] = LOH(h.z); f[5] = HIH(h.z); f[6] = LOH(h.w); f[7] = HIH(h.w);
    }
    if (MODE >= 1) {
      int c0 = cg * 8;
#pragma unroll
      for (int j = 0; j < 8; ++j)
        f[j] = fmaxf(f[j] * scsh[c0 + j] + scsh[128 + c0 + j], 0.f);
      if (MODE == 2 && valid) {
        uint4 rr = Rres[(size_t)(row0 + r) * 16 + cg];
        f[0] += LOH(rr.x); f[1] += HIH(rr.x);
        f[2] += LOH(rr.y); f[3] += HIH(rr.y);
        f[4] += LOH(rr.z); f[5] += HIH(rr.z);
        f[6] += LOH(rr.w); f[7] += HIH(rr.w);
      }
    }
    uint4 pk;
    pk.x = pkh(f[0], f[1]);
    pk.y = pkh(f[2], f[3]);
    pk.z = pkh(f[4], f[5]);
    pk.w = pkh(f[6], f[7]);
    if (MODE == 1 && valid) Rout[(size_t)(row0 + r) * 16 + cg] = pk;
    *(uint4*)&xs[r * 128 + ((cg ^ (r & 15)) << 3)] = pk;
  }
  __syncthreads();

  const int lane = t & 63;
  const int wave = t >> 6;
  const int arow = wave * 16 + (lane & 15);
  f16x8 a[4];
#pragma unroll
  for (int ks = 0; ks < 4; ++ks) {
    int cg = ks * 4 + (lane >> 4);
    a[ks] = *(const f16x8*)&xs[arow * 128 + ((cg ^ (arow & 15)) << 3)];
  }
  const f16x8* Wf = (const f16x8*)Wsw;
  f32x4 acc[NT];
#pragma unroll
  for (int nt = 0; nt < NT; ++nt) acc[nt] = (f32x4)(0.f);
#pragma unroll
  for (int nt = 0; nt < NT; ++nt) {
#pragma unroll
    for (int ks = 0; ks < 4; ++ks) {
      f16x8 b = Wf[(nt * 4 + ks) * 64 + lane];
      acc[nt] = __builtin_amdgcn_mfma_f32_16x16x32_f16(a[ks], b, acc[nt], 0, 0, 0);
    }
  }
  const int rbase = row0 + wave * 16 + (lane >> 4) * 4;
  const int cbase = lane & 15;
#pragma unroll
  for (int j = 0; j < 4; ++j) {
    int row = rbase + j;
    if (row < n) {
#pragma unroll
      for (int nt = 0; nt < NT; ++nt)
        Y[(size_t)row * NOUT + nt * 16 + cbase] =
            __half_as_ushort(__float2half(acc[nt][j]));
    }
  }
}

// ------------- CSR propagation over fp16 rows, F=128, fp16 out ----------
// out[d] = di * (sum_e u_e*T[src_e] + di*T[d]) + bias,  di = dinv[d].
__global__ __launch_bounds__(256) void k_propb128(const uint4* __restrict__ T,
    const float* __restrict__ dinv, const int* __restrict__ off,
    const unsigned int* __restrict__ erec, const float* __restrict__ bias,
    uint4* __restrict__ outv, int n) {
  constexpr int TPN = 16;
  int node = blockIdx.x * 16 + threadIdx.x / TPN;
  int f8 = threadIdx.x % TPN;
  if (node >= n) return;
  float di = dinv[node];
  float acc[8];
  {
    uint4 v = T[(size_t)node * TPN + f8];
    acc[0] = di * LOH(v.x); acc[1] = di * HIH(v.x);
    acc[2] = di * LOH(v.y); acc[3] = di * HIH(v.y);
    acc[4] = di * LOH(v.z); acc[5] = di * HIH(v.z);
    acc[6] = di * LOH(v.w); acc[7] = di * HIH(v.w);
  }
  int e = off[node], eend = off[node + 1];
  for (; e + 1 < eend; e += 2) {
    unsigned r0 = erec[e], r1 = erec[e + 1];
    uint4 v0 = T[(size_t)(r0 >> 16) * TPN + f8];
    uint4 v1 = T[(size_t)(r1 >> 16) * TPN + f8];
    float n0 = LOH(r0), n1 = LOH(r1);
    acc[0] = fmaf(n0, LOH(v0.x), acc[0]); acc[1] = fmaf(n0, HIH(v0.x), acc[1]);
    acc[2] = fmaf(n0, LOH(v0.y), acc[2]); acc[3] = fmaf(n0, HIH(v0.y), acc[3]);
    acc[4] = fmaf(n0, LOH(v0.z), acc[4]); acc[5] = fmaf(n0, HIH(v0.z), acc[5]);
    acc[6] = fmaf(n0, LOH(v0.w), acc[6]); acc[7] = fmaf(n0, HIH(v0.w), acc[7]);
    acc[0] = fmaf(n1, LOH(v1.x), acc[0]); acc[1] = fmaf(n1, HIH(v1.x), acc[1]);
    acc[2] = fmaf(n1, LOH(v1.y), acc[2]); acc[3] = fmaf(n1, HIH(v1.y), acc[3]);
    acc[4] = fmaf(n1, LOH(v1.z), acc[4]); acc[5] = fmaf(n1, HIH(v1.z), acc[5]);
    acc[6] = fmaf(n1, LOH(v1.w), acc[6]); acc[7] = fmaf(n1, HIH(v1.w), acc[7]);
  }
  if (e < eend) {
    unsigned r0 = erec[e];
    uint4 v0 = T[(size_t)(r0 >> 16) * TPN + f8];
    float n0 = LOH(r0);
    acc[0] = fmaf(n0, LOH(v0.x), acc[0]); acc[1] = fmaf(n0, HIH(v0.x), acc[1]);
    acc[2] = fmaf(n0, LOH(v0.y), acc[2]); acc[3] = fmaf(n0, HIH(v0.y), acc[3]);
    acc[4] = fmaf(n0, LOH(v0.z), acc[4]); acc[5] = fmaf(n0, HIH(v0.z), acc[5]);
    acc[6] = fmaf(n0, LOH(v0.w), acc[6]); acc[7] = fmaf(n0, HIH(v0.w), acc[7]);
  }
  float4 b0 = *(const float4*)&bias[f8 * 8];
  float4 b1 = *(const float4*)&bias[f8 * 8 + 4];
  uint4 pk;
  pk.x = pkh(fmaf(di, acc[0], b0.x), fmaf(di, acc[1], b0.y));
  pk.y = pkh(fmaf(di, acc[2], b0.z), fmaf(di, acc[3], b0.w));
  pk.z = pkh(fmaf(di, acc[4], b1.x), fmaf(di, acc[5], b1.y));
  pk.w = pkh(fmaf(di, acc[6], b1.z), fmaf(di, acc[7], b1.w));
  outv[(size_t)node * TPN + f8] = pk;
}

// ------------- heads prop (F=64) fused with reparameterization ----------
__global__ __launch_bounds__(256) void k_prop64_final(const uint4* __restrict__ T,
    const float* __restrict__ dinv, const int* __restrict__ off,
    const unsigned int* __restrict__ erec, const float* __restrict__ bias,
    const float* __restrict__ eps, float* __restrict__ out, int n) {
  constexpr int TPN = 8;
  int node = blockIdx.x * 32 + threadIdx.x / TPN;
  int f8 = threadIdx.x % TPN;
  if (node >= n) return;
  float di = dinv[node];
  float acc[8];
  {
    uint4 v = T[(size_t)node * TPN + f8];
    acc[0] = di * LOH(v.x); acc[1] = di * HIH(v.x);
    acc[2] = di * LOH(v.y); acc[3] = di * HIH(v.y);
    acc[4] = di * LOH(v.z); acc[5] = di * HIH(v.z);
    acc[6] = di * LOH(v.w); acc[7] = di * HIH(v.w);
  }
  int e = off[node], eend = off[node + 1];
  for (; e + 1 < eend; e += 2) {
    unsigned r0 = erec[e], r1 = erec[e + 1];
    uint4 v0 = T[(size_t)(r0 >> 16) * TPN + f8];
    uint4 v1 = T[(size_t)(r1 >> 16) * TPN + f8];
    float n0 = LOH(r0), n1 = LOH(r1);
    acc[0] = fmaf(n0, LOH(v0.x), acc[0]); acc[1] = fmaf(n0, HIH(v0.x), acc[1]);
    acc[2] = fmaf(n0, LOH(v0.y), acc[2]); acc[3] = fmaf(n0, HIH(v0.y), acc[3]);
    acc[4] = fmaf(n0, LOH(v0.z), acc[4]); acc[5] = fmaf(n0, HIH(v0.z), acc[5]);
    acc[6] = fmaf(n0, LOH(v0.w), acc[6]); acc[7] = fmaf(n0, HIH(v0.w), acc[7]);
    acc[0] = fmaf(n1, LOH(v1.x), acc[0]); acc[1] = fmaf(n1, HIH(v1.x), acc[1]);
    acc[2] = fmaf(n1, LOH(v1.y), acc[2]); acc[3] = fmaf(n1, HIH(v1.y), acc[3]);
    acc[4] = fmaf(n1, LOH(v1.z), acc[4]); acc[5] = fmaf(n1, HIH(v1.z), acc[5]);
    acc[6] = fmaf(n1, LOH(v1.w), acc[6]); acc[7] = fmaf(n1, HIH(v1.w), acc[7]);
  }
  if (e < eend) {
    unsigned r0 = erec[e];
    uint4 v0 = T[(size_t)(r0 >> 16) * TPN + f8];
    float n0 = LOH(r0);
    acc[0] = fmaf(n0, LOH(v0.x), acc[0]); acc[1] = fmaf(n0, HIH(v0.x), acc[1]);
    acc[2] = fmaf(n0, LOH(v0.y), acc[2]); acc[3] = fmaf(n0, HIH(v0.y), acc[3]);
    acc[4] = fmaf(n0, LOH(v0.z), acc[4]); acc[5] = fmaf(n0, HIH(v0.z), acc[5]);
    acc[6] = fmaf(n0, LOH(v0.w), acc[6]); acc[7] = fmaf(n0, HIH(v0.w), acc[7]);
  }
  float4 b0 = *(const float4*)&bias[f8 * 8];
  float4 b1 = *(const float4*)&bias[f8 * 8 + 4];
  float r[8];
  r[0] = fmaf(di, acc[0], b0.x); r[1] = fmaf(di, acc[1], b0.y);
  r[2] = fmaf(di, acc[2], b0.z); r[3] = fmaf(di, acc[3], b0.w);
  r[4] = fmaf(di, acc[4], b1.x); r[5] = fmaf(di, acc[5], b1.y);
  r[6] = fmaf(di, acc[6], b1.z); r[7] = fmaf(di, acc[7], b1.w);
  float p[8];
#pragma unroll
  for (int i = 0; i < 8; ++i) p[i] = __shfl_xor(r[i], 4);
  size_t M = (size_t)n * 32;
  if (f8 < 4) {
    int jb = f8 * 8;
    float4 e0 = *(const float4*)&eps[(size_t)node * 32 + jb];
    float4 e1 = *(const float4*)&eps[(size_t)node * 32 + jb + 4];
    float ev[8] = {e0.x, e0.y, e0.z, e0.w, e1.x, e1.y, e1.z, e1.w};
    float qz[8];
#pragma unroll
    for (int i = 0; i < 8; ++i) {
      float qs = p[i];
      float sp = fmaxf(qs, 0.f) + log1pf(expf(-fabsf(qs)));
      qz[i] = fmaf(sp + 1e-6f, ev[i], r[i]);
    }
    float* oz = &out[(size_t)node * 32 + jb];
    *(float4*)oz = make_float4(qz[0], qz[1], qz[2], qz[3]);
    *(float4*)(oz + 4) = make_float4(qz[4], qz[5], qz[6], qz[7]);
    float* om = &out[M + (size_t)node * 32 + jb];
    *(float4*)om = make_float4(r[0], r[1], r[2], r[3]);
    *(float4*)(om + 4) = make_float4(r[4], r[5], r[6], r[7]);
  } else {
    int jb = (f8 - 4) * 8;
    float* os = &out[2 * M + (size_t)node * 32 + jb];
    *(float4*)os = make_float4(r[0], r[1], r[2], r[3]);
    *(float4*)(os + 4) = make_float4(r[4], r[5], r[6], r[7]);
  }
}

// ---------------- BatchNorm stats (coalesced uint4 + wave/LDS reduce) ----
// thread: chunk = t&15 (8 cols), sub = t>>4 (node sublane). 128 blocks.
__global__ __launch_bounds__(256) void k_stats(const uint4* __restrict__ X4,
    float* __restrict__ stats, int n) {
  int t = threadIdx.x;
  int chunk = t & 15;
  int sub = t >> 4;
  float s[8] = {0, 0, 0, 0, 0, 0, 0, 0};
  float s2[8] = {0, 0, 0, 0, 0, 0, 0, 0};
  for (int node = blockIdx.x * 16 + sub; node < n; node += gridDim.x * 16) {
    uint4 v = X4[(size_t)node * 16 + chunk];
    float f[8] = {LOH(v.x), HIH(v.x), LOH(v.y), HIH(v.y),
                  LOH(v.z), HIH(v.z), LOH(v.w), HIH(v.w)};
#pragma unroll
    for (int i = 0; i < 8; ++i) { s[i] += f[i]; s2[i] += f[i] * f[i]; }
  }
  // reduce across sub bits within wave (lane bits 4,5)
#pragma unroll
  for (int m = 16; m <= 32; m <<= 1) {
#pragma unroll
    for (int i = 0; i < 8; ++i) {
      s[i] += __shfl_xor(s[i], m);
      s2[i] += __shfl_xor(s2[i], m);
    }
  }
  __shared__ float red[4][16][16];
  if ((t & 48) == 0) {  // one lane per (wave, chunk)
    int wv = t >> 6;
#pragma unroll
    for (int i = 0; i < 8; ++i) {
      red[wv][chunk][i] = s[i];
      red[wv][chunk][8 + i] = s2[i];
    }
  }
  __syncthreads();
  // 256 threads: t = chunk16*16 + j  -> combine 4 waves, 1 atomic each
  int c16 = t >> 4, j = t & 15;
  float v = red[0][c16][j] + red[1][c16][j] + red[2][c16][j] + red[3][c16][j];
  int col = c16 * 8 + (j & 7);
  atomicAdd(&stats[(j < 8) ? col : 128 + col], v);
}

// ---------------- launch ----------------

extern "C" void kernel_launch(void* const* d_in, const int* in_sizes, int n_in,
                              void* d_out, int out_size, void* d_ws, size_t ws_size,
                              hipStream_t stream) {
  const float* x  = (const float*)d_in[0];
  const int*   ei = (const int*)d_in[1];
  const float* ew = (const float*)d_in[2];
  const float* W0 = (const float*)d_in[3];
  const float* b0 = (const float*)d_in[4];
  const float* W1 = (const float*)d_in[5];
  const float* b1 = (const float*)d_in[6];
  const float* g0 = (const float*)d_in[7];
  const float* be0 = (const float*)d_in[8];
  const float* g1 = (const float*)d_in[9];
  const float* be1 = (const float*)d_in[10];
  const float* Wm = (const float*)d_in[11];
  const float* bm = (const float*)d_in[12];
  const float* Ws = (const float*)d_in[13];
  const float* bs = (const float*)d_in[14];
  const float* eps = (const float*)d_in[15];
  float* out = (float*)d_out;

  const int n = in_sizes[0] / HID;
  const int E = in_sizes[1] / 2;
  const int* esrc = ei;
  const int* edst = ei + E;

  char* base = (char*)d_ws;
  size_t cur = 0;
  auto alloc = [&](size_t bytes) {
    size_t o = cur;
    cur = (cur + bytes + 255) & ~(size_t)255;
    return (void*)(base + o);
  };
  unsigned long long* packed = (unsigned long long*)alloc((size_t)n * 8);
  float* dinv  = (float*)alloc((size_t)n * 4);
  int*   cnt   = (int*)alloc((size_t)n * 4);
  int*   coff  = (int*)alloc((size_t)(n + 1) * 4);
  unsigned short* rank = (unsigned short*)alloc((size_t)E * 2);
  unsigned int* erec = (unsigned int*)alloc((size_t)E * 4);
  int*   bsum  = (int*)alloc(64 * 4);
  int*   boff  = (int*)alloc(64 * 4);
  float* stats0 = (float*)alloc(256 * 4);
  float* stats1 = (float*)alloc(256 * 4);
  float* bcat  = (float*)alloc(64 * 4);
  uint4* Wsw0  = (uint4*)alloc(8 * 4 * 64 * 16);
  uint4* Wsw1  = (uint4*)alloc(8 * 4 * 64 * 16);
  uint4* Wswc  = (uint4*)alloc(4 * 4 * 64 * 16);
  unsigned short* bufA = (unsigned short*)alloc((size_t)n * 128 * 2);  // fp16
  unsigned short* bufB = (unsigned short*)alloc((size_t)n * 128 * 2);  // fp16
  unsigned short* bufC = (unsigned short*)alloc((size_t)n * 128 * 2);  // fp16 residual
  (void)ws_size;

  const int eb = (E + 255) / 256;
  const int gemmb = (n + BM - 1) / BM;
  const int scb = (n + SCH - 1) / SCH;

  // --- weight prep (no deps) ---
  k_wprep<128><<<8, 256, 0, stream>>>(W0, Wsw0);
  k_wprep<128><<<8, 256, 0, stream>>>(W1, Wsw1);
  k_wprepc<<<4, 256, 0, stream>>>(Wm, Ws, bm, bs, Wswc, bcat);

  // --- norm + CSR ---
  hipMemsetAsync(packed, 0, (size_t)n * 8, stream);
  hipMemsetAsync(stats0, 0, 256 * 4, stream);
  hipMemsetAsync(stats1, 0, 256 * 4, stream);
  k_deg_edges<<<eb, 256, 0, stream>>>(edst, ew, packed, rank, E);
  k_dinv_scan<<<scb, 256, 0, stream>>>(packed, dinv, cnt, bsum, n);
  k_scan_mid<<<1, 64, 0, stream>>>(bsum, boff, coff, scb, n);
  k_scan_out<<<scb, 256, 0, stream>>>(cnt, boff, coff, n);
  k_fill<<<eb, 256, 0, stream>>>(esrc, edst, ew, dinv, coff, rank, erec, E);

  // --- layer 0 ---
  k_gemm<128, 0><<<gemmb, 256, 0, stream>>>(x, Wsw0, bufA, n, nullptr, nullptr,
                                            nullptr, nullptr, nullptr);
  k_propb128<<<(n + 15) / 16, 256, 0, stream>>>((const uint4*)bufA, dinv, coff,
                                                erec, b0, (uint4*)bufB, n);
  k_stats<<<128, 256, 0, stream>>>((const uint4*)bufB, stats0, n);

  // --- layer 1 (BN0+relu in gemm staging; residual h0 -> bufC fp16) ---
  k_gemm<128, 1><<<gemmb, 256, 0, stream>>>(bufB, Wsw1, bufA, n, stats0, g0, be0,
                                            nullptr, (uint4*)bufC);
  k_propb128<<<(n + 15) / 16, 256, 0, stream>>>((const uint4*)bufA, dinv, coff,
                                                erec, b1, (uint4*)bufB, n);
  k_stats<<<128, 256, 0, stream>>>((const uint4*)bufB, stats1, n);

  // --- heads (BN1+relu+residual in gemm staging; mean||logstd) ---
  k_gemm<64, 2><<<gemmb, 256, 0, stream>>>(bufB, Wswc, bufA, n, stats1, g1, be1,
                                           (const uint4*)bufC, nullptr);
  k_prop64_final<<<(n + 31) / 32, 256, 0, stream>>>((const uint4*)bufA, dinv,
                                                    coff, erec, bcat, eps, out, n);
}

// Round 10
// 224.225 us; speedup vs baseline: 1.2394x; 1.0292x over previous
//
#include <hip/hip_runtime.h>
#include <hip/hip_bf16.h>
#include <hip/hip_fp16.h>
#include <math.h>

// GraphEncoderStack: 2x (GCNConv -> BN -> ReLU) + residual + 2 GCN heads + reparam
// N=50000 nodes, E=800000 edges, IN=HIDDEN=128, LATENT=32.
// MFMA f16 GEMM (fp32 accum); fp16 intermediates; fused epilogues.
// R10: grid-fusion of deg_edges (atomic-latency-bound) with gemm0 (compute).
// Requires n < 65536 (problem fixes n=50000).

#define HID 128
#define LAT 32

typedef _Float16 f16x8 __attribute__((ext_vector_type(8)));
typedef float f32x4 __attribute__((ext_vector_type(4)));

#define LOH(u) __half2float(__ushort_as_half((unsigned short)((u) & 0xFFFFu)))
#define HIH(u) __half2float(__ushort_as_half((unsigned short)((u) >> 16)))

__device__ __forceinline__ unsigned pkh(float a, float b) {
  return (unsigned)__half_as_ushort(__float2half(a)) |
         ((unsigned)__half_as_ushort(__float2half(b)) << 16);
}

// ---------------- MFMA GEMM body (shared by fused front + later layers) ----
// BM=64 rows/block, 4 waves; wave owns 16 rows x NOUT cols.
// MODE 0: fp32 X plain. MODE 1: fp16 X, BN(from stats,g,be)+relu, residual
// side-write. MODE 2: fp16 X, BN+relu+residual add.

#define BM 64
template <int NOUT, int MODE>
__device__ __forceinline__ void gemm_dev(int bid, const void* __restrict__ Xv,
    const uint4* __restrict__ Wsw, unsigned short* __restrict__ Y, int n,
    const float* __restrict__ stats, const float* __restrict__ g,
    const float* __restrict__ be, const uint4* __restrict__ Rres,
    uint4* __restrict__ Rout) {
  constexpr int NT = NOUT / 16;
  __shared__ _Float16 xs[BM * 128];
  __shared__ float scsh[256];
  const int t = threadIdx.x;
  const int row0 = bid * BM;
  if (MODE >= 1) {
    if (t < 128) {
      float m = stats[t] / (float)n;
      float var = fmaxf(stats[128 + t] / (float)n - m * m, 0.f);
      float sc = g[t] * rsqrtf(var + 1e-5f);
      scsh[t] = sc;
      scsh[128 + t] = be[t] - m * sc;
    }
    __syncthreads();
  }
  for (int i = t; i < BM * 16; i += 256) {
    int r = i >> 4, cg = i & 15;
    bool valid = (row0 + r) < n;
    float f[8];
    if (MODE == 0) {
      float4 v0 = make_float4(0.f, 0.f, 0.f, 0.f), v1 = v0;
      if (valid) {
        v0 = ((const float4*)Xv)[(size_t)(row0 + r) * 32 + cg * 2];
        v1 = ((const float4*)Xv)[(size_t)(row0 + r) * 32 + cg * 2 + 1];
      }
      f[0] = v0.x; f[1] = v0.y; f[2] = v0.z; f[3] = v0.w;
      f[4] = v1.x; f[5] = v1.y; f[6] = v1.z; f[7] = v1.w;
    } else {
      uint4 h = valid ? ((const uint4*)Xv)[(size_t)(row0 + r) * 16 + cg]
                      : make_uint4(0, 0, 0, 0);
      f[0] = LOH(h.x); f[1] = HIH(h.x); f[2] = LOH(h.y); f[3] = HIH(h.y);
      f[4] = LOH(h.z); f[5] = HIH(h.z); f[6] = LOH(h.w); f[7] = HIH(h.w);
    }
    if (MODE >= 1) {
      int c0 = cg * 8;
#pragma unroll
      for (int j = 0; j < 8; ++j)
        f[j] = fmaxf(f[j] * scsh[c0 + j] + scsh[128 + c0 + j], 0.f);
      if (MODE == 2 && valid) {
        uint4 rr = Rres[(size_t)(row0 + r) * 16 + cg];
        f[0] += LOH(rr.x); f[1] += HIH(rr.x);
        f[2] += LOH(rr.y); f[3] += HIH(rr.y);
        f[4] += LOH(rr.z); f[5] += HIH(rr.z);
        f[6] += LOH(rr.w); f[7] += HIH(rr.w);
      }
    }
    uint4 pk;
    pk.x = pkh(f[0], f[1]);
    pk.y = pkh(f[2], f[3]);
    pk.z = pkh(f[4], f[5]);
    pk.w = pkh(f[6], f[7]);
    if (MODE == 1 && valid) Rout[(size_t)(row0 + r) * 16 + cg] = pk;
    *(uint4*)&xs[r * 128 + ((cg ^ (r & 15)) << 3)] = pk;
  }
  __syncthreads();

  const int lane = t & 63;
  const int wave = t >> 6;
  const int arow = wave * 16 + (lane & 15);
  f16x8 a[4];
#pragma unroll
  for (int ks = 0; ks < 4; ++ks) {
    int cg = ks * 4 + (lane >> 4);
    a[ks] = *(const f16x8*)&xs[arow * 128 + ((cg ^ (arow & 15)) << 3)];
  }
  const f16x8* Wf = (const f16x8*)Wsw;
  f32x4 acc[NT];
#pragma unroll
  for (int nt = 0; nt < NT; ++nt) acc[nt] = (f32x4)(0.f);
#pragma unroll
  for (int nt = 0; nt < NT; ++nt) {
#pragma unroll
    for (int ks = 0; ks < 4; ++ks) {
      f16x8 b = Wf[(nt * 4 + ks) * 64 + lane];
      acc[nt] = __builtin_amdgcn_mfma_f32_16x16x32_f16(a[ks], b, acc[nt], 0, 0, 0);
    }
  }
  const int rbase = row0 + wave * 16 + (lane >> 4) * 4;
  const int cbase = lane & 15;
#pragma unroll
  for (int j = 0; j < 4; ++j) {
    int row = rbase + j;
    if (row < n) {
#pragma unroll
      for (int nt = 0; nt < NT; ++nt)
        Y[(size_t)row * NOUT + nt * 16 + cbase] =
            __half_as_ushort(__float2half(acc[nt][j]));
    }
  }
}

// ---------------- fused front: deg_edges atomics || gemm0 -----------------
// blocks [0,eb): packed[d] += (1<<48)|(w*2^24); rank[e] = old>>48.
// blocks [eb,eb+gemmb): layer-0 GEMM x @ W0 -> bufA (fp16).
__global__ __launch_bounds__(256) void k_front(const int* __restrict__ dst,
    const float* __restrict__ w, unsigned long long* __restrict__ packed,
    unsigned short* __restrict__ rank, int E, int eb,
    const float* __restrict__ x, const uint4* __restrict__ Wsw0,
    unsigned short* __restrict__ bufA, int n) {
  int b = blockIdx.x;
  if (b < eb) {
    int e = b * 256 + threadIdx.x;
    if (e < E) {
      int d = dst[e];
      unsigned long long v =
          (1ULL << 48) | (unsigned long long)(w[e] * 16777216.0f);
      unsigned long long old = atomicAdd(&packed[d], v);
      rank[e] = (unsigned short)(old >> 48);
    }
  } else {
    gemm_dev<128, 0>(b - eb, x, Wsw0, bufA, n, nullptr, nullptr, nullptr,
                     nullptr, nullptr);
  }
}

template <int NOUT, int MODE>
__global__ __launch_bounds__(256) void k_gemm(const void* __restrict__ Xv,
    const uint4* __restrict__ Wsw, unsigned short* __restrict__ Y, int n,
    const float* __restrict__ stats, const float* __restrict__ g,
    const float* __restrict__ be, const uint4* __restrict__ Rres,
    uint4* __restrict__ Rout) {
  gemm_dev<NOUT, MODE>(blockIdx.x, Xv, Wsw, Y, n, stats, g, be, Rres, Rout);
}

// ---------------- dinv + cnt + per-1024-chunk sum (fused) ----------------
#define SCH 1024

__global__ __launch_bounds__(256) void k_dinv_scan(
    const unsigned long long* __restrict__ packed, float* __restrict__ dinv,
    int* __restrict__ cnt, int* __restrict__ bsum, int n) {
  int t = threadIdx.x;
  int base = blockIdx.x * SCH + t * 4;
  int s = 0;
#pragma unroll
  for (int k = 0; k < 4; ++k) {
    int i = base + k;
    if (i < n) {
      unsigned long long p = packed[i];
      int c = (int)(p >> 48);
      cnt[i] = c;
      s += c;
      float d = (float)(p & 0xFFFFFFFFFFFFULL) * (1.0f / 16777216.0f) + 1.0f;
      dinv[i] = rsqrtf(d);
    }
  }
#pragma unroll
  for (int off = 32; off; off >>= 1) s += __shfl_down(s, off);
  __shared__ int ws[4];
  if ((t & 63) == 0) ws[t >> 6] = s;
  __syncthreads();
  if (t == 0) bsum[blockIdx.x] = ws[0] + ws[1] + ws[2] + ws[3];
}

// scan_out with inlined mid-scan: wave 0 scans bsum (nb <= 64) redundantly
// per block; no separate k_scan_mid launch.
__global__ __launch_bounds__(256) void k_scan_out(const int* __restrict__ cnt,
    const int* __restrict__ bsum, int* __restrict__ off, int nb, int n) {
  __shared__ int sboff;
  int t = threadIdx.x;
  if (t < 64) {
    int val = (t < nb) ? bsum[t] : 0;
    int inc = val;
#pragma unroll
    for (int d = 1; d < 64; d <<= 1) {
      int u = __shfl_up(inc, d);
      if (t >= d) inc += u;
    }
    // lane blockIdx.x holds inclusive sum up to itself
    int exc = inc - val;
    if (t == (int)blockIdx.x) sboff = exc;
    if (blockIdx.x == 0 && t == nb - 1) off[n] = inc;  // grand total
  }
  __syncthreads();
  int boff0 = sboff;
  int base = blockIdx.x * SCH + t * 4;
  int4 v = make_int4(0, 0, 0, 0);
  if (base + 3 < n) v = *(const int4*)&cnt[base];
  else {
    if (base + 0 < n) v.x = cnt[base + 0];
    if (base + 1 < n) v.y = cnt[base + 1];
    if (base + 2 < n) v.z = cnt[base + 2];
  }
  int s = v.x + v.y + v.z + v.w;
  int lane = t & 63, wv = t >> 6;
  int inc = s;
#pragma unroll
  for (int d = 1; d < 64; d <<= 1) {
    int u = __shfl_up(inc, d);
    if (lane >= d) inc += u;
  }
  __shared__ int wsum[4];
  if (lane == 63) wsum[wv] = inc;
  __syncthreads();
  int wbase = 0;
  for (int i = 0; i < wv; ++i) wbase += wsum[i];
  int ex = boff0 + wbase + inc - s;
  int4 o = make_int4(ex, ex + v.x, ex + v.x + v.y, ex + v.x + v.y + v.z);
  if (base + 3 < n) {
    *(int4*)&off[base] = o;
  } else {
    if (base + 0 < n) off[base + 0] = o.x;
    if (base + 1 < n) off[base + 1] = o.y;
    if (base + 2 < n) off[base + 2] = o.z;
  }
}

// CSR record: 4B = (src << 16) | fp16(w * dinv[src]); pos = coff[dst]+rank.
__global__ __launch_bounds__(256) void k_fill(const int* __restrict__ src,
    const int* __restrict__ dst, const float* __restrict__ w,
    const float* __restrict__ dinv, const int* __restrict__ coff,
    const unsigned short* __restrict__ rank, unsigned int* __restrict__ erec,
    int E) {
  int e = blockIdx.x * 256 + threadIdx.x;
  if (e < E) {
    int s = src[e], d = dst[e];
    int p = coff[d] + (int)rank[e];
    __half u = __float2half(w[e] * dinv[s]);
    erec[p] = ((unsigned)s << 16) | (unsigned)__half_as_ushort(u);
  }
}

// ---------------- W pre-swizzle into MFMA fragment order (fp16) ----------
template <int NOUT>
__global__ __launch_bounds__(256) void k_wprep(const float* __restrict__ W,
    uint4* __restrict__ Wsw) {
  int tid = blockIdx.x * 256 + threadIdx.x;
  if (tid >= (NOUT / 16) * 4 * 64) return;
  int l = tid & 63, ks = (tid >> 6) & 3, nt = tid >> 8;
  int col = nt * 16 + (l & 15);
  int kbase = ks * 32 + (l >> 4) * 8;
  _Float16 vals[8];
#pragma unroll
  for (int i = 0; i < 8; ++i) vals[i] = (_Float16)W[(kbase + i) * NOUT + col];
  Wsw[tid] = *(uint4*)vals;
}

// head weights: concat [Wm|Ws] virtually, swizzle for NOUT=64; also bcat.
__global__ __launch_bounds__(256) void k_wprepc(const float* __restrict__ Wm,
    const float* __restrict__ Ws, const float* __restrict__ bm,
    const float* __restrict__ bs, uint4* __restrict__ Wsw,
    float* __restrict__ bcat) {
  int tid = blockIdx.x * 256 + threadIdx.x;
  if (tid < 64) bcat[tid] = (tid < 32) ? bm[tid] : bs[tid - 32];
  if (tid >= 4 * 4 * 64) return;
  int l = tid & 63, ks = (tid >> 6) & 3, nt = tid >> 8;
  int col = nt * 16 + (l & 15);
  int kbase = ks * 32 + (l >> 4) * 8;
  const float* Wsrc = (col < 32) ? Wm : Ws;
  int c = (col < 32) ? col : col - 32;
  _Float16 vals[8];
#pragma unroll
  for (int i = 0; i < 8; ++i) vals[i] = (_Float16)Wsrc[(kbase + i) * 32 + c];
  Wsw[tid] = *(uint4*)vals;
}

// ------------- CSR propagation over fp16 rows, F=128, fp16 out ----------
__global__ __launch_bounds__(256) void k_propb128(const uint4* __restrict__ T,
    const float* __restrict__ dinv, const int* __restrict__ off,
    const unsigned int* __restrict__ erec, const float* __restrict__ bias,
    uint4* __restrict__ outv, int n) {
  constexpr int TPN = 16;
  int node = blockIdx.x * 16 + threadIdx.x / TPN;
  int f8 = threadIdx.x % TPN;
  if (node >= n) return;
  float di = dinv[node];
  float acc[8];
  {
    uint4 v = T[(size_t)node * TPN + f8];
    acc[0] = di * LOH(v.x); acc[1] = di * HIH(v.x);
    acc[2] = di * LOH(v.y); acc[3] = di * HIH(v.y);
    acc[4] = di * LOH(v.z); acc[5] = di * HIH(v.z);
    acc[6] = di * LOH(v.w); acc[7] = di * HIH(v.w);
  }
  int e = off[node], eend = off[node + 1];
  for (; e + 1 < eend; e += 2) {
    unsigned r0 = erec[e], r1 = erec[e + 1];
    uint4 v0 = T[(size_t)(r0 >> 16) * TPN + f8];
    uint4 v1 = T[(size_t)(r1 >> 16) * TPN + f8];
    float n0 = LOH(r0), n1 = LOH(r1);
    acc[0] = fmaf(n0, LOH(v0.x), acc[0]); acc[1] = fmaf(n0, HIH(v0.x), acc[1]);
    acc[2] = fmaf(n0, LOH(v0.y), acc[2]); acc[3] = fmaf(n0, HIH(v0.y), acc[3]);
    acc[4] = fmaf(n0, LOH(v0.z), acc[4]); acc[5] = fmaf(n0, HIH(v0.z), acc[5]);
    acc[6] = fmaf(n0, LOH(v0.w), acc[6]); acc[7] = fmaf(n0, HIH(v0.w), acc[7]);
    acc[0] = fmaf(n1, LOH(v1.x), acc[0]); acc[1] = fmaf(n1, HIH(v1.x), acc[1]);
    acc[2] = fmaf(n1, LOH(v1.y), acc[2]); acc[3] = fmaf(n1, HIH(v1.y), acc[3]);
    acc[4] = fmaf(n1, LOH(v1.z), acc[4]); acc[5] = fmaf(n1, HIH(v1.z), acc[5]);
    acc[6] = fmaf(n1, LOH(v1.w), acc[6]); acc[7] = fmaf(n1, HIH(v1.w), acc[7]);
  }
  if (e < eend) {
    unsigned r0 = erec[e];
    uint4 v0 = T[(size_t)(r0 >> 16) * TPN + f8];
    float n0 = LOH(r0);
    acc[0] = fmaf(n0, LOH(v0.x), acc[0]); acc[1] = fmaf(n0, HIH(v0.x), acc[1]);
    acc[2] = fmaf(n0, LOH(v0.y), acc[2]); acc[3] = fmaf(n0, HIH(v0.y), acc[3]);
    acc[4] = fmaf(n0, LOH(v0.z), acc[4]); acc[5] = fmaf(n0, HIH(v0.z), acc[5]);
    acc[6] = fmaf(n0, LOH(v0.w), acc[6]); acc[7] = fmaf(n0, HIH(v0.w), acc[7]);
  }
  float4 b0 = *(const float4*)&bias[f8 * 8];
  float4 b1 = *(const float4*)&bias[f8 * 8 + 4];
  uint4 pk;
  pk.x = pkh(fmaf(di, acc[0], b0.x), fmaf(di, acc[1], b0.y));
  pk.y = pkh(fmaf(di, acc[2], b0.z), fmaf(di, acc[3], b0.w));
  pk.z = pkh(fmaf(di, acc[4], b1.x), fmaf(di, acc[5], b1.y));
  pk.w = pkh(fmaf(di, acc[6], b1.z), fmaf(di, acc[7], b1.w));
  outv[(size_t)node * TPN + f8] = pk;
}

// ------------- heads prop (F=64) fused with reparameterization ----------
__global__ __launch_bounds__(256) void k_prop64_final(const uint4* __restrict__ T,
    const float* __restrict__ dinv, const int* __restrict__ off,
    const unsigned int* __restrict__ erec, const float* __restrict__ bias,
    const float* __restrict__ eps, float* __restrict__ out, int n) {
  constexpr int TPN = 8;
  int node = blockIdx.x * 32 + threadIdx.x / TPN;
  int f8 = threadIdx.x % TPN;
  if (node >= n) return;
  float di = dinv[node];
  float acc[8];
  {
    uint4 v = T[(size_t)node * TPN + f8];
    acc[0] = di * LOH(v.x); acc[1] = di * HIH(v.x);
    acc[2] = di * LOH(v.y); acc[3] = di * HIH(v.y);
    acc[4] = di * LOH(v.z); acc[5] = di * HIH(v.z);
    acc[6] = di * LOH(v.w); acc[7] = di * HIH(v.w);
  }
  int e = off[node], eend = off[node + 1];
  for (; e + 1 < eend; e += 2) {
    unsigned r0 = erec[e], r1 = erec[e + 1];
    uint4 v0 = T[(size_t)(r0 >> 16) * TPN + f8];
    uint4 v1 = T[(size_t)(r1 >> 16) * TPN + f8];
    float n0 = LOH(r0), n1 = LOH(r1);
    acc[0] = fmaf(n0, LOH(v0.x), acc[0]); acc[1] = fmaf(n0, HIH(v0.x), acc[1]);
    acc[2] = fmaf(n0, LOH(v0.y), acc[2]); acc[3] = fmaf(n0, HIH(v0.y), acc[3]);
    acc[4] = fmaf(n0, LOH(v0.z), acc[4]); acc[5] = fmaf(n0, HIH(v0.z), acc[5]);
    acc[6] = fmaf(n0, LOH(v0.w), acc[6]); acc[7] = fmaf(n0, HIH(v0.w), acc[7]);
    acc[0] = fmaf(n1, LOH(v1.x), acc[0]); acc[1] = fmaf(n1, HIH(v1.x), acc[1]);
    acc[2] = fmaf(n1, LOH(v1.y), acc[2]); acc[3] = fmaf(n1, HIH(v1.y), acc[3]);
    acc[4] = fmaf(n1, LOH(v1.z), acc[4]); acc[5] = fmaf(n1, HIH(v1.z), acc[5]);
    acc[6] = fmaf(n1, LOH(v1.w), acc[6]); acc[7] = fmaf(n1, HIH(v1.w), acc[7]);
  }
  if (e < eend) {
    unsigned r0 = erec[e];
    uint4 v0 = T[(size_t)(r0 >> 16) * TPN + f8];
    float n0 = LOH(r0);
    acc[0] = fmaf(n0, LOH(v0.x), acc[0]); acc[1] = fmaf(n0, HIH(v0.x), acc[1]);
    acc[2] = fmaf(n0, LOH(v0.y), acc[2]); acc[3] = fmaf(n0, HIH(v0.y), acc[3]);
    acc[4] = fmaf(n0, LOH(v0.z), acc[4]); acc[5] = fmaf(n0, HIH(v0.z), acc[5]);
    acc[6] = fmaf(n0, LOH(v0.w), acc[6]); acc[7] = fmaf(n0, HIH(v0.w), acc[7]);
  }
  float4 b0 = *(const float4*)&bias[f8 * 8];
  float4 b1 = *(const float4*)&bias[f8 * 8 + 4];
  float r[8];
  r[0] = fmaf(di, acc[0], b0.x); r[1] = fmaf(di, acc[1], b0.y);
  r[2] = fmaf(di, acc[2], b0.z); r[3] = fmaf(di, acc[3], b0.w);
  r[4] = fmaf(di, acc[4], b1.x); r[5] = fmaf(di, acc[5], b1.y);
  r[6] = fmaf(di, acc[6], b1.z); r[7] = fmaf(di, acc[7], b1.w);
  float p[8];
#pragma unroll
  for (int i = 0; i < 8; ++i) p[i] = __shfl_xor(r[i], 4);
  size_t M = (size_t)n * 32;
  if (f8 < 4) {
    int jb = f8 * 8;
    float4 e0 = *(const float4*)&eps[(size_t)node * 32 + jb];
    float4 e1 = *(const float4*)&eps[(size_t)node * 32 + jb + 4];
    float ev[8] = {e0.x, e0.y, e0.z, e0.w, e1.x, e1.y, e1.z, e1.w};
    float qz[8];
#pragma unroll
    for (int i = 0; i < 8; ++i) {
      float qs = p[i];
      float sp = fmaxf(qs, 0.f) + log1pf(expf(-fabsf(qs)));
      qz[i] = fmaf(sp + 1e-6f, ev[i], r[i]);
    }
    float* oz = &out[(size_t)node * 32 + jb];
    *(float4*)oz = make_float4(qz[0], qz[1], qz[2], qz[3]);
    *(float4*)(oz + 4) = make_float4(qz[4], qz[5], qz[6], qz[7]);
    float* om = &out[M + (size_t)node * 32 + jb];
    *(float4*)om = make_float4(r[0], r[1], r[2], r[3]);
    *(float4*)(om + 4) = make_float4(r[4], r[5], r[6], r[7]);
  } else {
    int jb = (f8 - 4) * 8;
    float* os = &out[2 * M + (size_t)node * 32 + jb];
    *(float4*)os = make_float4(r[0], r[1], r[2], r[3]);
    *(float4*)(os + 4) = make_float4(r[4], r[5], r[6], r[7]);
  }
}

// ---------------- BatchNorm stats (coalesced uint4 + wave/LDS reduce) ----
__global__ __launch_bounds__(256) void k_stats(const uint4* __restrict__ X4,
    float* __restrict__ stats, int n) {
  int t = threadIdx.x;
  int chunk = t & 15;
  int sub = t >> 4;
  float s[8] = {0, 0, 0, 0, 0, 0, 0, 0};
  float s2[8] = {0, 0, 0, 0, 0, 0, 0, 0};
  for (int node = blockIdx.x * 16 + sub; node < n; node += gridDim.x * 16) {
    uint4 v = X4[(size_t)node * 16 + chunk];
    float f[8] = {LOH(v.x), HIH(v.x), LOH(v.y), HIH(v.y),
                  LOH(v.z), HIH(v.z), LOH(v.w), HIH(v.w)};
#pragma unroll
    for (int i = 0; i < 8; ++i) { s[i] += f[i]; s2[i] += f[i] * f[i]; }
  }
#pragma unroll
  for (int m = 16; m <= 32; m <<= 1) {
#pragma unroll
    for (int i = 0; i < 8; ++i) {
      s[i] += __shfl_xor(s[i], m);
      s2[i] += __shfl_xor(s2[i], m);
    }
  }
  __shared__ float red[4][16][16];
  if ((t & 48) == 0) {
    int wv = t >> 6;
#pragma unroll
    for (int i = 0; i < 8; ++i) {
      red[wv][chunk][i] = s[i];
      red[wv][chunk][8 + i] = s2[i];
    }
  }
  __syncthreads();
  int c16 = t >> 4, j = t & 15;
  float v = red[0][c16][j] + red[1][c16][j] + red[2][c16][j] + red[3][c16][j];
  int col = c16 * 8 + (j & 7);
  atomicAdd(&stats[(j < 8) ? col : 128 + col], v);
}

// ---------------- launch ----------------

extern "C" void kernel_launch(void* const* d_in, const int* in_sizes, int n_in,
                              void* d_out, int out_size, void* d_ws, size_t ws_size,
                              hipStream_t stream) {
  const float* x  = (const float*)d_in[0];
  const int*   ei = (const int*)d_in[1];
  const float* ew = (const float*)d_in[2];
  const float* W0 = (const float*)d_in[3];
  const float* b0 = (const float*)d_in[4];
  const float* W1 = (const float*)d_in[5];
  const float* b1 = (const float*)d_in[6];
  const float* g0 = (const float*)d_in[7];
  const float* be0 = (const float*)d_in[8];
  const float* g1 = (const float*)d_in[9];
  const float* be1 = (const float*)d_in[10];
  const float* Wm = (const float*)d_in[11];
  const float* bm = (const float*)d_in[12];
  const float* Ws = (const float*)d_in[13];
  const float* bs = (const float*)d_in[14];
  const float* eps = (const float*)d_in[15];
  float* out = (float*)d_out;

  const int n = in_sizes[0] / HID;
  const int E = in_sizes[1] / 2;
  const int* esrc = ei;
  const int* edst = ei + E;

  char* base = (char*)d_ws;
  size_t cur = 0;
  auto alloc = [&](size_t bytes) {
    size_t o = cur;
    cur = (cur + bytes + 255) & ~(size_t)255;
    return (void*)(base + o);
  };
  unsigned long long* packed = (unsigned long long*)alloc((size_t)n * 8);
  float* dinv  = (float*)alloc((size_t)n * 4);
  int*   cnt   = (int*)alloc((size_t)n * 4);
  int*   coff  = (int*)alloc((size_t)(n + 1) * 4);
  unsigned short* rank = (unsigned short*)alloc((size_t)E * 2);
  unsigned int* erec = (unsigned int*)alloc((size_t)E * 4);
  int*   bsum  = (int*)alloc(64 * 4);
  float* stats0 = (float*)alloc(256 * 4);
  float* stats1 = (float*)alloc(256 * 4);
  float* bcat  = (float*)alloc(64 * 4);
  uint4* Wsw0  = (uint4*)alloc(8 * 4 * 64 * 16);
  uint4* Wsw1  = (uint4*)alloc(8 * 4 * 64 * 16);
  uint4* Wswc  = (uint4*)alloc(4 * 4 * 64 * 16);
  unsigned short* bufA = (unsigned short*)alloc((size_t)n * 128 * 2);  // fp16
  unsigned short* bufB = (unsigned short*)alloc((size_t)n * 128 * 2);  // fp16
  unsigned short* bufC = (unsigned short*)alloc((size_t)n * 128 * 2);  // fp16 residual
  (void)ws_size;

  const int eb = (E + 255) / 256;
  const int gemmb = (n + BM - 1) / BM;
  const int scb = (n + SCH - 1) / SCH;

  // --- weight prep (no deps; Wsw0 must precede k_front's gemm path) ---
  k_wprep<128><<<8, 256, 0, stream>>>(W0, Wsw0);
  k_wprep<128><<<8, 256, 0, stream>>>(W1, Wsw1);
  k_wprepc<<<4, 256, 0, stream>>>(Wm, Ws, bm, bs, Wswc, bcat);
  hipMemsetAsync(packed, 0, (size_t)n * 8, stream);
  hipMemsetAsync(stats0, 0, 256 * 4, stream);
  hipMemsetAsync(stats1, 0, 256 * 4, stream);

  // --- fused: edge-degree atomics || layer-0 GEMM ---
  k_front<<<eb + gemmb, 256, 0, stream>>>(edst, ew, packed, rank, E, eb,
                                          x, Wsw0, bufA, n);

  // --- CSR ---
  k_dinv_scan<<<scb, 256, 0, stream>>>(packed, dinv, cnt, bsum, n);
  k_scan_out<<<scb, 256, 0, stream>>>(cnt, bsum, coff, scb, n);
  k_fill<<<eb, 256, 0, stream>>>(esrc, edst, ew, dinv, coff, rank, erec, E);

  // --- layer 0 prop + stats ---
  k_propb128<<<(n + 15) / 16, 256, 0, stream>>>((const uint4*)bufA, dinv, coff,
                                                erec, b0, (uint4*)bufB, n);
  k_stats<<<128, 256, 0, stream>>>((const uint4*)bufB, stats0, n);

  // --- layer 1 (BN0+relu in gemm staging; residual h0 -> bufC fp16) ---
  k_gemm<128, 1><<<gemmb, 256, 0, stream>>>(bufB, Wsw1, bufA, n, stats0, g0, be0,
                                            nullptr, (uint4*)bufC);
  k_propb128<<<(n + 15) / 16, 256, 0, stream>>>((const uint4*)bufA, dinv, coff,
                                                erec, b1, (uint4*)bufB, n);
  k_stats<<<128, 256, 0, stream>>>((const uint4*)bufB, stats1, n);

  // --- heads (BN1+relu+residual in gemm staging; mean||logstd) ---
  k_gemm<64, 2><<<gemmb, 256, 0, stream>>>(bufB, Wswc, bufA, n, stats1, g1, be1,
                                           (const uint4*)bufC, nullptr);
  k_prop64_final<<<(n + 31) / 32, 256, 0, stream>>>((const uint4*)bufA, dinv,
                                                    coff, erec, bcat, eps, out, n);
}

// Round 11
// 208.983 us; speedup vs baseline: 1.3298x; 1.0729x over previous
//
#include <hip/hip_runtime.h>
#include <hip/hip_bf16.h>
#include <hip/hip_fp16.h>
#include <math.h>

// GraphEncoderStack: 2x (GCNConv -> BN -> ReLU) + residual + 2 GCN heads + reparam
// N=50000 nodes, E=800000 edges, IN=HIDDEN=128, LATENT=32.
// MFMA f16 GEMM (fp32 accum); fp16 intermediates; fused epilogues.
// R11: gemm-first role order in k_front; single prep kernel.
// Requires n < 65536 (problem fixes n=50000).

#define HID 128
#define LAT 32

typedef _Float16 f16x8 __attribute__((ext_vector_type(8)));
typedef float f32x4 __attribute__((ext_vector_type(4)));

#define LOH(u) __half2float(__ushort_as_half((unsigned short)((u) & 0xFFFFu)))
#define HIH(u) __half2float(__ushort_as_half((unsigned short)((u) >> 16)))

__device__ __forceinline__ unsigned pkh(float a, float b) {
  return (unsigned)__half_as_ushort(__float2half(a)) |
         ((unsigned)__half_as_ushort(__float2half(b)) << 16);
}

// ---------------- MFMA GEMM body ----------------
// BM=64 rows/block, 4 waves; wave owns 16 rows x NOUT cols.
// MODE 0: fp32 X plain. MODE 1: fp16 X, BN(from stats,g,be)+relu, residual
// side-write. MODE 2: fp16 X, BN+relu+residual add.

#define BM 64
template <int NOUT, int MODE>
__device__ __forceinline__ void gemm_dev(int bid, const void* __restrict__ Xv,
    const uint4* __restrict__ Wsw, unsigned short* __restrict__ Y, int n,
    const float* __restrict__ stats, const float* __restrict__ g,
    const float* __restrict__ be, const uint4* __restrict__ Rres,
    uint4* __restrict__ Rout) {
  constexpr int NT = NOUT / 16;
  __shared__ _Float16 xs[BM * 128];
  __shared__ float scsh[256];
  const int t = threadIdx.x;
  const int row0 = bid * BM;
  if (MODE >= 1) {
    if (t < 128) {
      float m = stats[t] / (float)n;
      float var = fmaxf(stats[128 + t] / (float)n - m * m, 0.f);
      float sc = g[t] * rsqrtf(var + 1e-5f);
      scsh[t] = sc;
      scsh[128 + t] = be[t] - m * sc;
    }
    __syncthreads();
  }
  for (int i = t; i < BM * 16; i += 256) {
    int r = i >> 4, cg = i & 15;
    bool valid = (row0 + r) < n;
    float f[8];
    if (MODE == 0) {
      float4 v0 = make_float4(0.f, 0.f, 0.f, 0.f), v1 = v0;
      if (valid) {
        v0 = ((const float4*)Xv)[(size_t)(row0 + r) * 32 + cg * 2];
        v1 = ((const float4*)Xv)[(size_t)(row0 + r) * 32 + cg * 2 + 1];
      }
      f[0] = v0.x; f[1] = v0.y; f[2] = v0.z; f[3] = v0.w;
      f[4] = v1.x; f[5] = v1.y; f[6] = v1.z; f[7] = v1.w;
    } else {
      uint4 h = valid ? ((const uint4*)Xv)[(size_t)(row0 + r) * 16 + cg]
                      : make_uint4(0, 0, 0, 0);
      f[0] = LOH(h.x); f[1] = HIH(h.x); f[2] = LOH(h.y); f[3] = HIH(h.y);
      f[4] = LOH(h.z); f[5] = HIH(h.z); f[6] = LOH(h.w); f[7] = HIH(h.w);
    }
    if (MODE >= 1) {
      int c0 = cg * 8;
#pragma unroll
      for (int j = 0; j < 8; ++j)
        f[j] = fmaxf(f[j] * scsh[c0 + j] + scsh[128 + c0 + j], 0.f);
      if (MODE == 2 && valid) {
        uint4 rr = Rres[(size_t)(row0 + r) * 16 + cg];
        f[0] += LOH(rr.x); f[1] += HIH(rr.x);
        f[2] += LOH(rr.y); f[3] += HIH(rr.y);
        f[4] += LOH(rr.z); f[5] += HIH(rr.z);
        f[6] += LOH(rr.w); f[7] += HIH(rr.w);
      }
    }
    uint4 pk;
    pk.x = pkh(f[0], f[1]);
    pk.y = pkh(f[2], f[3]);
    pk.z = pkh(f[4], f[5]);
    pk.w = pkh(f[6], f[7]);
    if (MODE == 1 && valid) Rout[(size_t)(row0 + r) * 16 + cg] = pk;
    *(uint4*)&xs[r * 128 + ((cg ^ (r & 15)) << 3)] = pk;
  }
  __syncthreads();

  const int lane = t & 63;
  const int wave = t >> 6;
  const int arow = wave * 16 + (lane & 15);
  f16x8 a[4];
#pragma unroll
  for (int ks = 0; ks < 4; ++ks) {
    int cg = ks * 4 + (lane >> 4);
    a[ks] = *(const f16x8*)&xs[arow * 128 + ((cg ^ (arow & 15)) << 3)];
  }
  const f16x8* Wf = (const f16x8*)Wsw;
  f32x4 acc[NT];
#pragma unroll
  for (int nt = 0; nt < NT; ++nt) acc[nt] = (f32x4)(0.f);
#pragma unroll
  for (int nt = 0; nt < NT; ++nt) {
#pragma unroll
    for (int ks = 0; ks < 4; ++ks) {
      f16x8 b = Wf[(nt * 4 + ks) * 64 + lane];
      acc[nt] = __builtin_amdgcn_mfma_f32_16x16x32_f16(a[ks], b, acc[nt], 0, 0, 0);
    }
  }
  const int rbase = row0 + wave * 16 + (lane >> 4) * 4;
  const int cbase = lane & 15;
#pragma unroll
  for (int j = 0; j < 4; ++j) {
    int row = rbase + j;
    if (row < n) {
#pragma unroll
      for (int nt = 0; nt < NT; ++nt)
        Y[(size_t)row * NOUT + nt * 16 + cbase] =
            __half_as_ushort(__float2half(acc[nt][j]));
    }
  }
}

// ---------------- fused front: gemm0 (first) || deg_edges atomics ---------
// blocks [0,gemmb): layer-0 GEMM x @ W0 -> bufA (fp16) -- dispatched first so
// the compute runs under the atomic-latency shadow of the edge blocks.
// blocks [gemmb,gemmb+eb): packed[d] += (1<<48)|(w*2^24); rank[e] = old>>48.
__global__ __launch_bounds__(256) void k_front(const int* __restrict__ dst,
    const float* __restrict__ w, unsigned long long* __restrict__ packed,
    unsigned short* __restrict__ rank, int E, int gemmb,
    const float* __restrict__ x, const uint4* __restrict__ Wsw0,
    unsigned short* __restrict__ bufA, int n) {
  int b = blockIdx.x;
  if (b < gemmb) {
    gemm_dev<128, 0>(b, x, Wsw0, bufA, n, nullptr, nullptr, nullptr,
                     nullptr, nullptr);
  } else {
    int e = (b - gemmb) * 256 + threadIdx.x;
    if (e < E) {
      int d = dst[e];
      unsigned long long v =
          (1ULL << 48) | (unsigned long long)(w[e] * 16777216.0f);
      unsigned long long old = atomicAdd(&packed[d], v);
      rank[e] = (unsigned short)(old >> 48);
    }
  }
}

template <int NOUT, int MODE>
__global__ __launch_bounds__(256) void k_gemm(const void* __restrict__ Xv,
    const uint4* __restrict__ Wsw, unsigned short* __restrict__ Y, int n,
    const float* __restrict__ stats, const float* __restrict__ g,
    const float* __restrict__ be, const uint4* __restrict__ Rres,
    uint4* __restrict__ Rout) {
  gemm_dev<NOUT, MODE>(blockIdx.x, Xv, Wsw, Y, n, stats, g, be, Rres, Rout);
}

// ---------------- prep: W swizzles + bcat + zero packed/stats (one launch) --
// blocks 0-7: W0 swizzle; 8-15: W1 swizzle; 16-19: head swizzle (+bcat);
// 20: zero stats; 21+: zero packed.
__global__ __launch_bounds__(256) void k_prep(const float* __restrict__ W0,
    const float* __restrict__ W1, const float* __restrict__ Wm,
    const float* __restrict__ Ws, const float* __restrict__ bm,
    const float* __restrict__ bs, uint4* __restrict__ Wsw0,
    uint4* __restrict__ Wsw1, uint4* __restrict__ Wswc,
    float* __restrict__ bcat, unsigned long long* __restrict__ packed,
    float* __restrict__ stats0, float* __restrict__ stats1, int n) {
  int b = blockIdx.x;
  int t = threadIdx.x;
  if (b < 16) {
    // W0 / W1 swizzle for NOUT=128: tid in [0, 8*4*64)
    const float* W = (b < 8) ? W0 : W1;
    uint4* Wsw = (b < 8) ? Wsw0 : Wsw1;
    int tid = (b & 7) * 256 + t;
    int l = tid & 63, ks = (tid >> 6) & 3, nt = tid >> 8;
    int col = nt * 16 + (l & 15);
    int kbase = ks * 32 + (l >> 4) * 8;
    _Float16 vals[8];
#pragma unroll
    for (int i = 0; i < 8; ++i) vals[i] = (_Float16)W[(kbase + i) * 128 + col];
    Wsw[tid] = *(uint4*)vals;
  } else if (b < 20) {
    int tid = (b - 16) * 256 + t;
    if (tid < 64) bcat[tid] = (tid < 32) ? bm[tid] : bs[tid - 32];
    int l = tid & 63, ks = (tid >> 6) & 3, nt = tid >> 8;
    int col = nt * 16 + (l & 15);
    int kbase = ks * 32 + (l >> 4) * 8;
    const float* Wsrc = (col < 32) ? Wm : Ws;
    int c = (col < 32) ? col : col - 32;
    _Float16 vals[8];
#pragma unroll
    for (int i = 0; i < 8; ++i) vals[i] = (_Float16)Wsrc[(kbase + i) * 32 + c];
    Wswc[tid] = *(uint4*)vals;
  } else if (b == 20) {
    stats0[t] = 0.f;
    stats1[t] = 0.f;
  } else {
    int i = (b - 21) * 256 + t;
    if (i < n) packed[i] = 0ULL;
  }
}

// ---------------- dinv + cnt + per-1024-chunk sum (fused) ----------------
#define SCH 1024

__global__ __launch_bounds__(256) void k_dinv_scan(
    const unsigned long long* __restrict__ packed, float* __restrict__ dinv,
    int* __restrict__ cnt, int* __restrict__ bsum, int n) {
  int t = threadIdx.x;
  int base = blockIdx.x * SCH + t * 4;
  int s = 0;
#pragma unroll
  for (int k = 0; k < 4; ++k) {
    int i = base + k;
    if (i < n) {
      unsigned long long p = packed[i];
      int c = (int)(p >> 48);
      cnt[i] = c;
      s += c;
      float d = (float)(p & 0xFFFFFFFFFFFFULL) * (1.0f / 16777216.0f) + 1.0f;
      dinv[i] = rsqrtf(d);
    }
  }
#pragma unroll
  for (int off = 32; off; off >>= 1) s += __shfl_down(s, off);
  __shared__ int ws[4];
  if ((t & 63) == 0) ws[t >> 6] = s;
  __syncthreads();
  if (t == 0) bsum[blockIdx.x] = ws[0] + ws[1] + ws[2] + ws[3];
}

// scan_out with inlined mid-scan: wave 0 scans bsum (nb <= 64) redundantly.
__global__ __launch_bounds__(256) void k_scan_out(const int* __restrict__ cnt,
    const int* __restrict__ bsum, int* __restrict__ off, int nb, int n) {
  __shared__ int sboff;
  int t = threadIdx.x;
  if (t < 64) {
    int val = (t < nb) ? bsum[t] : 0;
    int inc = val;
#pragma unroll
    for (int d = 1; d < 64; d <<= 1) {
      int u = __shfl_up(inc, d);
      if (t >= d) inc += u;
    }
    int exc = inc - val;
    if (t == (int)blockIdx.x) sboff = exc;
    if (blockIdx.x == 0 && t == nb - 1) off[n] = inc;
  }
  __syncthreads();
  int boff0 = sboff;
  int base = blockIdx.x * SCH + t * 4;
  int4 v = make_int4(0, 0, 0, 0);
  if (base + 3 < n) v = *(const int4*)&cnt[base];
  else {
    if (base + 0 < n) v.x = cnt[base + 0];
    if (base + 1 < n) v.y = cnt[base + 1];
    if (base + 2 < n) v.z = cnt[base + 2];
  }
  int s = v.x + v.y + v.z + v.w;
  int lane = t & 63, wv = t >> 6;
  int inc = s;
#pragma unroll
  for (int d = 1; d < 64; d <<= 1) {
    int u = __shfl_up(inc, d);
    if (lane >= d) inc += u;
  }
  __shared__ int wsum[4];
  if (lane == 63) wsum[wv] = inc;
  __syncthreads();
  int wbase = 0;
  for (int i = 0; i < wv; ++i) wbase += wsum[i];
  int ex = boff0 + wbase + inc - s;
  int4 o = make_int4(ex, ex + v.x, ex + v.x + v.y, ex + v.x + v.y + v.z);
  if (base + 3 < n) {
    *(int4*)&off[base] = o;
  } else {
    if (base + 0 < n) off[base + 0] = o.x;
    if (base + 1 < n) off[base + 1] = o.y;
    if (base + 2 < n) off[base + 2] = o.z;
  }
}

// CSR record: 4B = (src << 16) | fp16(w * dinv[src]); pos = coff[dst]+rank.
__global__ __launch_bounds__(256) void k_fill(const int* __restrict__ src,
    const int* __restrict__ dst, const float* __restrict__ w,
    const float* __restrict__ dinv, const int* __restrict__ coff,
    const unsigned short* __restrict__ rank, unsigned int* __restrict__ erec,
    int E) {
  int e = blockIdx.x * 256 + threadIdx.x;
  if (e < E) {
    int s = src[e], d = dst[e];
    int p = coff[d] + (int)rank[e];
    __half u = __float2half(w[e] * dinv[s]);
    erec[p] = ((unsigned)s << 16) | (unsigned)__half_as_ushort(u);
  }
}

// ------------- CSR propagation over fp16 rows, F=128, fp16 out ----------
__global__ __launch_bounds__(256) void k_propb128(const uint4* __restrict__ T,
    const float* __restrict__ dinv, const int* __restrict__ off,
    const unsigned int* __restrict__ erec, const float* __restrict__ bias,
    uint4* __restrict__ outv, int n) {
  constexpr int TPN = 16;
  int node = blockIdx.x * 16 + threadIdx.x / TPN;
  int f8 = threadIdx.x % TPN;
  if (node >= n) return;
  float di = dinv[node];
  float acc[8];
  {
    uint4 v = T[(size_t)node * TPN + f8];
    acc[0] = di * LOH(v.x); acc[1] = di * HIH(v.x);
    acc[2] = di * LOH(v.y); acc[3] = di * HIH(v.y);
    acc[4] = di * LOH(v.z); acc[5] = di * HIH(v.z);
    acc[6] = di * LOH(v.w); acc[7] = di * HIH(v.w);
  }
  int e = off[node], eend = off[node + 1];
  for (; e + 1 < eend; e += 2) {
    unsigned r0 = erec[e], r1 = erec[e + 1];
    uint4 v0 = T[(size_t)(r0 >> 16) * TPN + f8];
    uint4 v1 = T[(size_t)(r1 >> 16) * TPN + f8];
    float n0 = LOH(r0), n1 = LOH(r1);
    acc[0] = fmaf(n0, LOH(v0.x), acc[0]); acc[1] = fmaf(n0, HIH(v0.x), acc[1]);
    acc[2] = fmaf(n0, LOH(v0.y), acc[2]); acc[3] = fmaf(n0, HIH(v0.y), acc[3]);
    acc[4] = fmaf(n0, LOH(v0.z), acc[4]); acc[5] = fmaf(n0, HIH(v0.z), acc[5]);
    acc[6] = fmaf(n0, LOH(v0.w), acc[6]); acc[7] = fmaf(n0, HIH(v0.w), acc[7]);
    acc[0] = fmaf(n1, LOH(v1.x), acc[0]); acc[1] = fmaf(n1, HIH(v1.x), acc[1]);
    acc[2] = fmaf(n1, LOH(v1.y), acc[2]); acc[3] = fmaf(n1, HIH(v1.y), acc[3]);
    acc[4] = fmaf(n1, LOH(v1.z), acc[4]); acc[5] = fmaf(n1, HIH(v1.z), acc[5]);
    acc[6] = fmaf(n1, LOH(v1.w), acc[6]); acc[7] = fmaf(n1, HIH(v1.w), acc[7]);
  }
  if (e < eend) {
    unsigned r0 = erec[e];
    uint4 v0 = T[(size_t)(r0 >> 16) * TPN + f8];
    float n0 = LOH(r0);
    acc[0] = fmaf(n0, LOH(v0.x), acc[0]); acc[1] = fmaf(n0, HIH(v0.x), acc[1]);
    acc[2] = fmaf(n0, LOH(v0.y), acc[2]); acc[3] = fmaf(n0, HIH(v0.y), acc[3]);
    acc[4] = fmaf(n0, LOH(v0.z), acc[4]); acc[5] = fmaf(n0, HIH(v0.z), acc[5]);
    acc[6] = fmaf(n0, LOH(v0.w), acc[6]); acc[7] = fmaf(n0, HIH(v0.w), acc[7]);
  }
  float4 b0 = *(const float4*)&bias[f8 * 8];
  float4 b1 = *(const float4*)&bias[f8 * 8 + 4];
  uint4 pk;
  pk.x = pkh(fmaf(di, acc[0], b0.x), fmaf(di, acc[1], b0.y));
  pk.y = pkh(fmaf(di, acc[2], b0.z), fmaf(di, acc[3], b0.w));
  pk.z = pkh(fmaf(di, acc[4], b1.x), fmaf(di, acc[5], b1.y));
  pk.w = pkh(fmaf(di, acc[6], b1.z), fmaf(di, acc[7], b1.w));
  outv[(size_t)node * TPN + f8] = pk;
}

// ------------- heads prop (F=64) fused with reparameterization ----------
__global__ __launch_bounds__(256) void k_prop64_final(const uint4* __restrict__ T,
    const float* __restrict__ dinv, const int* __restrict__ off,
    const unsigned int* __restrict__ erec, const float* __restrict__ bias,
    const float* __restrict__ eps, float* __restrict__ out, int n) {
  constexpr int TPN = 8;
  int node = blockIdx.x * 32 + threadIdx.x / TPN;
  int f8 = threadIdx.x % TPN;
  if (node >= n) return;
  float di = dinv[node];
  float acc[8];
  {
    uint4 v = T[(size_t)node * TPN + f8];
    acc[0] = di * LOH(v.x); acc[1] = di * HIH(v.x);
    acc[2] = di * LOH(v.y); acc[3] = di * HIH(v.y);
    acc[4] = di * LOH(v.z); acc[5] = di * HIH(v.z);
    acc[6] = di * LOH(v.w); acc[7] = di * HIH(v.w);
  }
  int e = off[node], eend = off[node + 1];
  for (; e + 1 < eend; e += 2) {
    unsigned r0 = erec[e], r1 = erec[e + 1];
    uint4 v0 = T[(size_t)(r0 >> 16) * TPN + f8];
    uint4 v1 = T[(size_t)(r1 >> 16) * TPN + f8];
    float n0 = LOH(r0), n1 = LOH(r1);
    acc[0] = fmaf(n0, LOH(v0.x), acc[0]); acc[1] = fmaf(n0, HIH(v0.x), acc[1]);
    acc[2] = fmaf(n0, LOH(v0.y), acc[2]); acc[3] = fmaf(n0, HIH(v0.y), acc[3]);
    acc[4] = fmaf(n0, LOH(v0.z), acc[4]); acc[5] = fmaf(n0, HIH(v0.z), acc[5]);
    acc[6] = fmaf(n0, LOH(v0.w), acc[6]); acc[7] = fmaf(n0, HIH(v0.w), acc[7]);
    acc[0] = fmaf(n1, LOH(v1.x), acc[0]); acc[1] = fmaf(n1, HIH(v1.x), acc[1]);
    acc[2] = fmaf(n1, LOH(v1.y), acc[2]); acc[3] = fmaf(n1, HIH(v1.y), acc[3]);
    acc[4] = fmaf(n1, LOH(v1.z), acc[4]); acc[5] = fmaf(n1, HIH(v1.z), acc[5]);
    acc[6] = fmaf(n1, LOH(v1.w), acc[6]); acc[7] = fmaf(n1, HIH(v1.w), acc[7]);
  }
  if (e < eend) {
    unsigned r0 = erec[e];
    uint4 v0 = T[(size_t)(r0 >> 16) * TPN + f8];
    float n0 = LOH(r0);
    acc[0] = fmaf(n0, LOH(v0.x), acc[0]); acc[1] = fmaf(n0, HIH(v0.x), acc[1]);
    acc[2] = fmaf(n0, LOH(v0.y), acc[2]); acc[3] = fmaf(n0, HIH(v0.y), acc[3]);
    acc[4] = fmaf(n0, LOH(v0.z), acc[4]); acc[5] = fmaf(n0, HIH(v0.z), acc[5]);
    acc[6] = fmaf(n0, LOH(v0.w), acc[6]); acc[7] = fmaf(n0, HIH(v0.w), acc[7]);
  }
  float4 b0 = *(const float4*)&bias[f8 * 8];
  float4 b1 = *(const float4*)&bias[f8 * 8 + 4];
  float r[8];
  r[0] = fmaf(di, acc[0], b0.x); r[1] = fmaf(di, acc[1], b0.y);
  r[2] = fmaf(di, acc[2], b0.z); r[3] = fmaf(di, acc[3], b0.w);
  r[4] = fmaf(di, acc[4], b1.x); r[5] = fmaf(di, acc[5], b1.y);
  r[6] = fmaf(di, acc[6], b1.z); r[7] = fmaf(di, acc[7], b1.w);
  float p[8];
#pragma unroll
  for (int i = 0; i < 8; ++i) p[i] = __shfl_xor(r[i], 4);
  size_t M = (size_t)n * 32;
  if (f8 < 4) {
    int jb = f8 * 8;
    float4 e0 = *(const float4*)&eps[(size_t)node * 32 + jb];
    float4 e1 = *(const float4*)&eps[(size_t)node * 32 + jb + 4];
    float ev[8] = {e0.x, e0.y, e0.z, e0.w, e1.x, e1.y, e1.z, e1.w};
    float qz[8];
#pragma unroll
    for (int i = 0; i < 8; ++i) {
      float qs = p[i];
      float sp = fmaxf(qs, 0.f) + log1pf(expf(-fabsf(qs)));
      qz[i] = fmaf(sp + 1e-6f, ev[i], r[i]);
    }
    float* oz = &out[(size_t)node * 32 + jb];
    *(float4*)oz = make_float4(qz[0], qz[1], qz[2], qz[3]);
    *(float4*)(oz + 4) = make_float4(qz[4], qz[5], qz[6], qz[7]);
    float* om = &out[M + (size_t)node * 32 + jb];
    *(float4*)om = make_float4(r[0], r[1], r[2], r[3]);
    *(float4*)(om + 4) = make_float4(r[4], r[5], r[6], r[7]);
  } else {
    int jb = (f8 - 4) * 8;
    float* os = &out[2 * M + (size_t)node * 32 + jb];
    *(float4*)os = make_float4(r[0], r[1], r[2], r[3]);
    *(float4*)(os + 4) = make_float4(r[4], r[5], r[6], r[7]);
  }
}

// ---------------- BatchNorm stats (coalesced uint4 + wave/LDS reduce) ----
__global__ __launch_bounds__(256) void k_stats(const uint4* __restrict__ X4,
    float* __restrict__ stats, int n) {
  int t = threadIdx.x;
  int chunk = t & 15;
  int sub = t >> 4;
  float s[8] = {0, 0, 0, 0, 0, 0, 0, 0};
  float s2[8] = {0, 0, 0, 0, 0, 0, 0, 0};
  for (int node = blockIdx.x * 16 + sub; node < n; node += gridDim.x * 16) {
    uint4 v = X4[(size_t)node * 16 + chunk];
    float f[8] = {LOH(v.x), HIH(v.x), LOH(v.y), HIH(v.y),
                  LOH(v.z), HIH(v.z), LOH(v.w), HIH(v.w)};
#pragma unroll
    for (int i = 0; i < 8; ++i) { s[i] += f[i]; s2[i] += f[i] * f[i]; }
  }
#pragma unroll
  for (int m = 16; m <= 32; m <<= 1) {
#pragma unroll
    for (int i = 0; i < 8; ++i) {
      s[i] += __shfl_xor(s[i], m);
      s2[i] += __shfl_xor(s2[i], m);
    }
  }
  __shared__ float red[4][16][16];
  if ((t & 48) == 0) {
    int wv = t >> 6;
#pragma unroll
    for (int i = 0; i < 8; ++i) {
      red[wv][chunk][i] = s[i];
      red[wv][chunk][8 + i] = s2[i];
    }
  }
  __syncthreads();
  int c16 = t >> 4, j = t & 15;
  float v = red[0][c16][j] + red[1][c16][j] + red[2][c16][j] + red[3][c16][j];
  int col = c16 * 8 + (j & 7);
  atomicAdd(&stats[(j < 8) ? col : 128 + col], v);
}

// ---------------- launch ----------------

extern "C" void kernel_launch(void* const* d_in, const int* in_sizes, int n_in,
                              void* d_out, int out_size, void* d_ws, size_t ws_size,
                              hipStream_t stream) {
  const float* x  = (const float*)d_in[0];
  const int*   ei = (const int*)d_in[1];
  const float* ew = (const float*)d_in[2];
  const float* W0 = (const float*)d_in[3];
  const float* b0 = (const float*)d_in[4];
  const float* W1 = (const float*)d_in[5];
  const float* b1 = (const float*)d_in[6];
  const float* g0 = (const float*)d_in[7];
  const float* be0 = (const float*)d_in[8];
  const float* g1 = (const float*)d_in[9];
  const float* be1 = (const float*)d_in[10];
  const float* Wm = (const float*)d_in[11];
  const float* bm = (const float*)d_in[12];
  const float* Ws = (const float*)d_in[13];
  const float* bs = (const float*)d_in[14];
  const float* eps = (const float*)d_in[15];
  float* out = (float*)d_out;

  const int n = in_sizes[0] / HID;
  const int E = in_sizes[1] / 2;
  const int* esrc = ei;
  const int* edst = ei + E;

  char* base = (char*)d_ws;
  size_t cur = 0;
  auto alloc = [&](size_t bytes) {
    size_t o = cur;
    cur = (cur + bytes + 255) & ~(size_t)255;
    return (void*)(base + o);
  };
  unsigned long long* packed = (unsigned long long*)alloc((size_t)n * 8);
  float* dinv  = (float*)alloc((size_t)n * 4);
  int*   cnt   = (int*)alloc((size_t)n * 4);
  int*   coff  = (int*)alloc((size_t)(n + 1) * 4);
  unsigned short* rank = (unsigned short*)alloc((size_t)E * 2);
  unsigned int* erec = (unsigned int*)alloc((size_t)E * 4);
  int*   bsum  = (int*)alloc(64 * 4);
  float* stats0 = (float*)alloc(256 * 4);
  float* stats1 = (float*)alloc(256 * 4);
  float* bcat  = (float*)alloc(64 * 4);
  uint4* Wsw0  = (uint4*)alloc(8 * 4 * 64 * 16);
  uint4* Wsw1  = (uint4*)alloc(8 * 4 * 64 * 16);
  uint4* Wswc  = (uint4*)alloc(4 * 4 * 64 * 16);
  unsigned short* bufA = (unsigned short*)alloc((size_t)n * 128 * 2);  // fp16
  unsigned short* bufB = (unsigned short*)alloc((size_t)n * 128 * 2);  // fp16
  unsigned short* bufC = (unsigned short*)alloc((size_t)n * 128 * 2);  // fp16 residual
  (void)ws_size;

  const int eb = (E + 255) / 256;
  const int gemmb = (n + BM - 1) / BM;
  const int scb = (n + SCH - 1) / SCH;
  const int prepb = 21 + (n + 255) / 256;

  // --- prep: W swizzles + zero packed/stats, one launch ---
  k_prep<<<prepb, 256, 0, stream>>>(W0, W1, Wm, Ws, bm, bs, Wsw0, Wsw1, Wswc,
                                    bcat, packed, stats0, stats1, n);

  // --- fused: layer-0 GEMM (first) || edge-degree atomics ---
  k_front<<<gemmb + eb, 256, 0, stream>>>(edst, ew, packed, rank, E, gemmb,
                                          x, Wsw0, bufA, n);

  // --- CSR ---
  k_dinv_scan<<<scb, 256, 0, stream>>>(packed, dinv, cnt, bsum, n);
  k_scan_out<<<scb, 256, 0, stream>>>(cnt, bsum, coff, scb, n);
  k_fill<<<eb, 256, 0, stream>>>(esrc, edst, ew, dinv, coff, rank, erec, E);

  // --- layer 0 prop + stats ---
  k_propb128<<<(n + 15) / 16, 256, 0, stream>>>((const uint4*)bufA, dinv, coff,
                                                erec, b0, (uint4*)bufB, n);
  k_stats<<<128, 256, 0, stream>>>((const uint4*)bufB, stats0, n);

  // --- layer 1 (BN0+relu in gemm staging; residual h0 -> bufC fp16) ---
  k_gemm<128, 1><<<gemmb, 256, 0, stream>>>(bufB, Wsw1, bufA, n, stats0, g0, be0,
                                            nullptr, (uint4*)bufC);
  k_propb128<<<(n + 15) / 16, 256, 0, stream>>>((const uint4*)bufA, dinv, coff,
                                                erec, b1, (uint4*)bufB, n);
  k_stats<<<128, 256, 0, stream>>>((const uint4*)bufB, stats1, n);

  // --- heads (BN1+relu+residual in gemm staging; mean||logstd) ---
  k_gemm<64, 2><<<gemmb, 256, 0, stream>>>(bufB, Wswc, bufA, n, stats1, g1, be1,
                                           (const uint4*)bufC, nullptr);
  k_prop64_final<<<(n + 31) / 32, 256, 0, stream>>>((const uint4*)bufA, dinv,
                                                    coff, erec, bcat, eps, out, n);
}

// Round 12
// 204.642 us; speedup vs baseline: 1.3580x; 1.0212x over previous
//
#include <hip/hip_runtime.h>
#include <hip/hip_bf16.h>
#include <hip/hip_fp16.h>
#include <math.h>

// GraphEncoderStack: 2x (GCNConv -> BN -> ReLU) + residual + 2 GCN heads + reparam
// N=50000 nodes, E=800000 edges, IN=HIDDEN=128, LATENT=32.
// MFMA f16 GEMM (fp32 accum); fp16 intermediates; fused epilogues.
// R12: 4 edges/thread in atomic/scatter kernels; 4-edge gather unroll in props.
// Requires n < 65536 (problem fixes n=50000).

#define HID 128
#define LAT 32

typedef _Float16 f16x8 __attribute__((ext_vector_type(8)));
typedef float f32x4 __attribute__((ext_vector_type(4)));

#define LOH(u) __half2float(__ushort_as_half((unsigned short)((u) & 0xFFFFu)))
#define HIH(u) __half2float(__ushort_as_half((unsigned short)((u) >> 16)))

__device__ __forceinline__ unsigned pkh(float a, float b) {
  return (unsigned)__half_as_ushort(__float2half(a)) |
         ((unsigned)__half_as_ushort(__float2half(b)) << 16);
}

// ---------------- MFMA GEMM body ----------------
// BM=64 rows/block, 4 waves; wave owns 16 rows x NOUT cols.
// MODE 0: fp32 X plain. MODE 1: fp16 X, BN(from stats,g,be)+relu, residual
// side-write. MODE 2: fp16 X, BN+relu+residual add.

#define BM 64
template <int NOUT, int MODE>
__device__ __forceinline__ void gemm_dev(int bid, const void* __restrict__ Xv,
    const uint4* __restrict__ Wsw, unsigned short* __restrict__ Y, int n,
    const float* __restrict__ stats, const float* __restrict__ g,
    const float* __restrict__ be, const uint4* __restrict__ Rres,
    uint4* __restrict__ Rout) {
  constexpr int NT = NOUT / 16;
  __shared__ _Float16 xs[BM * 128];
  __shared__ float scsh[256];
  const int t = threadIdx.x;
  const int row0 = bid * BM;
  if (MODE >= 1) {
    if (t < 128) {
      float m = stats[t] / (float)n;
      float var = fmaxf(stats[128 + t] / (float)n - m * m, 0.f);
      float sc = g[t] * rsqrtf(var + 1e-5f);
      scsh[t] = sc;
      scsh[128 + t] = be[t] - m * sc;
    }
    __syncthreads();
  }
  for (int i = t; i < BM * 16; i += 256) {
    int r = i >> 4, cg = i & 15;
    bool valid = (row0 + r) < n;
    float f[8];
    if (MODE == 0) {
      float4 v0 = make_float4(0.f, 0.f, 0.f, 0.f), v1 = v0;
      if (valid) {
        v0 = ((const float4*)Xv)[(size_t)(row0 + r) * 32 + cg * 2];
        v1 = ((const float4*)Xv)[(size_t)(row0 + r) * 32 + cg * 2 + 1];
      }
      f[0] = v0.x; f[1] = v0.y; f[2] = v0.z; f[3] = v0.w;
      f[4] = v1.x; f[5] = v1.y; f[6] = v1.z; f[7] = v1.w;
    } else {
      uint4 h = valid ? ((const uint4*)Xv)[(size_t)(row0 + r) * 16 + cg]
                      : make_uint4(0, 0, 0, 0);
      f[0] = LOH(h.x); f[1] = HIH(h.x); f[2] = LOH(h.y); f[3] = HIH(h.y);
      f[4] = LOH(h.z); f[5] = HIH(h.z); f[6] = LOH(h.w); f[7] = HIH(h.w);
    }
    if (MODE >= 1) {
      int c0 = cg * 8;
#pragma unroll
      for (int j = 0; j < 8; ++j)
        f[j] = fmaxf(f[j] * scsh[c0 + j] + scsh[128 + c0 + j], 0.f);
      if (MODE == 2 && valid) {
        uint4 rr = Rres[(size_t)(row0 + r) * 16 + cg];
        f[0] += LOH(rr.x); f[1] += HIH(rr.x);
        f[2] += LOH(rr.y); f[3] += HIH(rr.y);
        f[4] += LOH(rr.z); f[5] += HIH(rr.z);
        f[6] += LOH(rr.w); f[7] += HIH(rr.w);
      }
    }
    uint4 pk;
    pk.x = pkh(f[0], f[1]);
    pk.y = pkh(f[2], f[3]);
    pk.z = pkh(f[4], f[5]);
    pk.w = pkh(f[6], f[7]);
    if (MODE == 1 && valid) Rout[(size_t)(row0 + r) * 16 + cg] = pk;
    *(uint4*)&xs[r * 128 + ((cg ^ (r & 15)) << 3)] = pk;
  }
  __syncthreads();

  const int lane = t & 63;
  const int wave = t >> 6;
  const int arow = wave * 16 + (lane & 15);
  f16x8 a[4];
#pragma unroll
  for (int ks = 0; ks < 4; ++ks) {
    int cg = ks * 4 + (lane >> 4);
    a[ks] = *(const f16x8*)&xs[arow * 128 + ((cg ^ (arow & 15)) << 3)];
  }
  const f16x8* Wf = (const f16x8*)Wsw;
  f32x4 acc[NT];
#pragma unroll
  for (int nt = 0; nt < NT; ++nt) acc[nt] = (f32x4)(0.f);
#pragma unroll
  for (int nt = 0; nt < NT; ++nt) {
#pragma unroll
    for (int ks = 0; ks < 4; ++ks) {
      f16x8 b = Wf[(nt * 4 + ks) * 64 + lane];
      acc[nt] = __builtin_amdgcn_mfma_f32_16x16x32_f16(a[ks], b, acc[nt], 0, 0, 0);
    }
  }
  const int rbase = row0 + wave * 16 + (lane >> 4) * 4;
  const int cbase = lane & 15;
#pragma unroll
  for (int j = 0; j < 4; ++j) {
    int row = rbase + j;
    if (row < n) {
#pragma unroll
      for (int nt = 0; nt < NT; ++nt)
        Y[(size_t)row * NOUT + nt * 16 + cbase] =
            __half_as_ushort(__float2half(acc[nt][j]));
    }
  }
}

// ---------------- fused front: gemm0 (first) || deg_edges atomics ---------
// blocks [0,gemmb): layer-0 GEMM x @ W0 -> bufA (fp16).
// blocks [gemmb,...): 4 edges/thread, 4 independent packed atomics in flight.
__global__ __launch_bounds__(256) void k_front(const int* __restrict__ dst,
    const float* __restrict__ w, unsigned long long* __restrict__ packed,
    unsigned short* __restrict__ rank, int E, int gemmb,
    const float* __restrict__ x, const uint4* __restrict__ Wsw0,
    unsigned short* __restrict__ bufA, int n) {
  int b = blockIdx.x;
  if (b < gemmb) {
    gemm_dev<128, 0>(b, x, Wsw0, bufA, n, nullptr, nullptr, nullptr,
                     nullptr, nullptr);
  } else {
    int idx0 = (b - gemmb) * 1024 + threadIdx.x;
#pragma unroll
    for (int k = 0; k < 4; ++k) {
      int e = idx0 + k * 256;
      if (e < E) {
        int d = dst[e];
        unsigned long long v =
            (1ULL << 48) | (unsigned long long)(w[e] * 16777216.0f);
        unsigned long long old = atomicAdd(&packed[d], v);
        rank[e] = (unsigned short)(old >> 48);
      }
    }
  }
}

template <int NOUT, int MODE>
__global__ __launch_bounds__(256) void k_gemm(const void* __restrict__ Xv,
    const uint4* __restrict__ Wsw, unsigned short* __restrict__ Y, int n,
    const float* __restrict__ stats, const float* __restrict__ g,
    const float* __restrict__ be, const uint4* __restrict__ Rres,
    uint4* __restrict__ Rout) {
  gemm_dev<NOUT, MODE>(blockIdx.x, Xv, Wsw, Y, n, stats, g, be, Rres, Rout);
}

// ---------------- prep: W swizzles + bcat + zero packed/stats (one launch) --
__global__ __launch_bounds__(256) void k_prep(const float* __restrict__ W0,
    const float* __restrict__ W1, const float* __restrict__ Wm,
    const float* __restrict__ Ws, const float* __restrict__ bm,
    const float* __restrict__ bs, uint4* __restrict__ Wsw0,
    uint4* __restrict__ Wsw1, uint4* __restrict__ Wswc,
    float* __restrict__ bcat, unsigned long long* __restrict__ packed,
    float* __restrict__ stats0, float* __restrict__ stats1, int n) {
  int b = blockIdx.x;
  int t = threadIdx.x;
  if (b < 16) {
    const float* W = (b < 8) ? W0 : W1;
    uint4* Wsw = (b < 8) ? Wsw0 : Wsw1;
    int tid = (b & 7) * 256 + t;
    int l = tid & 63, ks = (tid >> 6) & 3, nt = tid >> 8;
    int col = nt * 16 + (l & 15);
    int kbase = ks * 32 + (l >> 4) * 8;
    _Float16 vals[8];
#pragma unroll
    for (int i = 0; i < 8; ++i) vals[i] = (_Float16)W[(kbase + i) * 128 + col];
    Wsw[tid] = *(uint4*)vals;
  } else if (b < 20) {
    int tid = (b - 16) * 256 + t;
    if (tid < 64) bcat[tid] = (tid < 32) ? bm[tid] : bs[tid - 32];
    int l = tid & 63, ks = (tid >> 6) & 3, nt = tid >> 8;
    int col = nt * 16 + (l & 15);
    int kbase = ks * 32 + (l >> 4) * 8;
    const float* Wsrc = (col < 32) ? Wm : Ws;
    int c = (col < 32) ? col : col - 32;
    _Float16 vals[8];
#pragma unroll
    for (int i = 0; i < 8; ++i) vals[i] = (_Float16)Wsrc[(kbase + i) * 32 + c];
    Wswc[tid] = *(uint4*)vals;
  } else if (b == 20) {
    stats0[t] = 0.f;
    stats1[t] = 0.f;
  } else {
    int i = (b - 21) * 256 + t;
    if (i < n) packed[i] = 0ULL;
  }
}

// ---------------- dinv + cnt + per-1024-chunk sum (fused) ----------------
#define SCH 1024

__global__ __launch_bounds__(256) void k_dinv_scan(
    const unsigned long long* __restrict__ packed, float* __restrict__ dinv,
    int* __restrict__ cnt, int* __restrict__ bsum, int n) {
  int t = threadIdx.x;
  int base = blockIdx.x * SCH + t * 4;
  int s = 0;
#pragma unroll
  for (int k = 0; k < 4; ++k) {
    int i = base + k;
    if (i < n) {
      unsigned long long p = packed[i];
      int c = (int)(p >> 48);
      cnt[i] = c;
      s += c;
      float d = (float)(p & 0xFFFFFFFFFFFFULL) * (1.0f / 16777216.0f) + 1.0f;
      dinv[i] = rsqrtf(d);
    }
  }
#pragma unroll
  for (int off = 32; off; off >>= 1) s += __shfl_down(s, off);
  __shared__ int ws[4];
  if ((t & 63) == 0) ws[t >> 6] = s;
  __syncthreads();
  if (t == 0) bsum[blockIdx.x] = ws[0] + ws[1] + ws[2] + ws[3];
}

// scan_out with inlined mid-scan: wave 0 scans bsum (nb <= 64) redundantly.
__global__ __launch_bounds__(256) void k_scan_out(const int* __restrict__ cnt,
    const int* __restrict__ bsum, int* __restrict__ off, int nb, int n) {
  __shared__ int sboff;
  int t = threadIdx.x;
  if (t < 64) {
    int val = (t < nb) ? bsum[t] : 0;
    int inc = val;
#pragma unroll
    for (int d = 1; d < 64; d <<= 1) {
      int u = __shfl_up(inc, d);
      if (t >= d) inc += u;
    }
    int exc = inc - val;
    if (t == (int)blockIdx.x) sboff = exc;
    if (blockIdx.x == 0 && t == nb - 1) off[n] = inc;
  }
  __syncthreads();
  int boff0 = sboff;
  int base = blockIdx.x * SCH + t * 4;
  int4 v = make_int4(0, 0, 0, 0);
  if (base + 3 < n) v = *(const int4*)&cnt[base];
  else {
    if (base + 0 < n) v.x = cnt[base + 0];
    if (base + 1 < n) v.y = cnt[base + 1];
    if (base + 2 < n) v.z = cnt[base + 2];
  }
  int s = v.x + v.y + v.z + v.w;
  int lane = t & 63, wv = t >> 6;
  int inc = s;
#pragma unroll
  for (int d = 1; d < 64; d <<= 1) {
    int u = __shfl_up(inc, d);
    if (lane >= d) inc += u;
  }
  __shared__ int wsum[4];
  if (lane == 63) wsum[wv] = inc;
  __syncthreads();
  int wbase = 0;
  for (int i = 0; i < wv; ++i) wbase += wsum[i];
  int ex = boff0 + wbase + inc - s;
  int4 o = make_int4(ex, ex + v.x, ex + v.x + v.y, ex + v.x + v.y + v.z);
  if (base + 3 < n) {
    *(int4*)&off[base] = o;
  } else {
    if (base + 0 < n) off[base + 0] = o.x;
    if (base + 1 < n) off[base + 1] = o.y;
    if (base + 2 < n) off[base + 2] = o.z;
  }
}

// CSR record: 4B = (src << 16) | fp16(w * dinv[src]); pos = coff[dst]+rank.
// 4 edges/thread for deeper scatter pipeline.
__global__ __launch_bounds__(256) void k_fill(const int* __restrict__ src,
    const int* __restrict__ dst, const float* __restrict__ w,
    const float* __restrict__ dinv, const int* __restrict__ coff,
    const unsigned short* __restrict__ rank, unsigned int* __restrict__ erec,
    int E) {
  int idx0 = blockIdx.x * 1024 + threadIdx.x;
#pragma unroll
  for (int k = 0; k < 4; ++k) {
    int e = idx0 + k * 256;
    if (e < E) {
      int s = src[e], d = dst[e];
      int p = coff[d] + (int)rank[e];
      __half u = __float2half(w[e] * dinv[s]);
      erec[p] = ((unsigned)s << 16) | (unsigned)__half_as_ushort(u);
    }
  }
}

// ------------- CSR propagation over fp16 rows, F=128, fp16 out ----------
// 4-edge unroll: 4 independent 16B gathers in flight per thread.
__global__ __launch_bounds__(256) void k_propb128(const uint4* __restrict__ T,
    const float* __restrict__ dinv, const int* __restrict__ off,
    const unsigned int* __restrict__ erec, const float* __restrict__ bias,
    uint4* __restrict__ outv, int n) {
  constexpr int TPN = 16;
  int node = blockIdx.x * 16 + threadIdx.x / TPN;
  int f8 = threadIdx.x % TPN;
  if (node >= n) return;
  float di = dinv[node];
  float acc[8];
  {
    uint4 v = T[(size_t)node * TPN + f8];
    acc[0] = di * LOH(v.x); acc[1] = di * HIH(v.x);
    acc[2] = di * LOH(v.y); acc[3] = di * HIH(v.y);
    acc[4] = di * LOH(v.z); acc[5] = di * HIH(v.z);
    acc[6] = di * LOH(v.w); acc[7] = di * HIH(v.w);
  }
  int e = off[node], eend = off[node + 1];
  for (; e + 3 < eend; e += 4) {
    unsigned r0 = erec[e], r1 = erec[e + 1], r2 = erec[e + 2], r3 = erec[e + 3];
    uint4 v0 = T[(size_t)(r0 >> 16) * TPN + f8];
    uint4 v1 = T[(size_t)(r1 >> 16) * TPN + f8];
    uint4 v2 = T[(size_t)(r2 >> 16) * TPN + f8];
    uint4 v3 = T[(size_t)(r3 >> 16) * TPN + f8];
    float n0 = LOH(r0), n1 = LOH(r1), n2 = LOH(r2), n3 = LOH(r3);
    acc[0] = fmaf(n0, LOH(v0.x), acc[0]); acc[1] = fmaf(n0, HIH(v0.x), acc[1]);
    acc[2] = fmaf(n0, LOH(v0.y), acc[2]); acc[3] = fmaf(n0, HIH(v0.y), acc[3]);
    acc[4] = fmaf(n0, LOH(v0.z), acc[4]); acc[5] = fmaf(n0, HIH(v0.z), acc[5]);
    acc[6] = fmaf(n0, LOH(v0.w), acc[6]); acc[7] = fmaf(n0, HIH(v0.w), acc[7]);
    acc[0] = fmaf(n1, LOH(v1.x), acc[0]); acc[1] = fmaf(n1, HIH(v1.x), acc[1]);
    acc[2] = fmaf(n1, LOH(v1.y), acc[2]); acc[3] = fmaf(n1, HIH(v1.y), acc[3]);
    acc[4] = fmaf(n1, LOH(v1.z), acc[4]); acc[5] = fmaf(n1, HIH(v1.z), acc[5]);
    acc[6] = fmaf(n1, LOH(v1.w), acc[6]); acc[7] = fmaf(n1, HIH(v1.w), acc[7]);
    acc[0] = fmaf(n2, LOH(v2.x), acc[0]); acc[1] = fmaf(n2, HIH(v2.x), acc[1]);
    acc[2] = fmaf(n2, LOH(v2.y), acc[2]); acc[3] = fmaf(n2, HIH(v2.y), acc[3]);
    acc[4] = fmaf(n2, LOH(v2.z), acc[4]); acc[5] = fmaf(n2, HIH(v2.z), acc[5]);
    acc[6] = fmaf(n2, LOH(v2.w), acc[6]); acc[7] = fmaf(n2, HIH(v2.w), acc[7]);
    acc[0] = fmaf(n3, LOH(v3.x), acc[0]); acc[1] = fmaf(n3, HIH(v3.x), acc[1]);
    acc[2] = fmaf(n3, LOH(v3.y), acc[2]); acc[3] = fmaf(n3, HIH(v3.y), acc[3]);
    acc[4] = fmaf(n3, LOH(v3.z), acc[4]); acc[5] = fmaf(n3, HIH(v3.z), acc[5]);
    acc[6] = fmaf(n3, LOH(v3.w), acc[6]); acc[7] = fmaf(n3, HIH(v3.w), acc[7]);
  }
  for (; e < eend; ++e) {
    unsigned r0 = erec[e];
    uint4 v0 = T[(size_t)(r0 >> 16) * TPN + f8];
    float n0 = LOH(r0);
    acc[0] = fmaf(n0, LOH(v0.x), acc[0]); acc[1] = fmaf(n0, HIH(v0.x), acc[1]);
    acc[2] = fmaf(n0, LOH(v0.y), acc[2]); acc[3] = fmaf(n0, HIH(v0.y), acc[3]);
    acc[4] = fmaf(n0, LOH(v0.z), acc[4]); acc[5] = fmaf(n0, HIH(v0.z), acc[5]);
    acc[6] = fmaf(n0, LOH(v0.w), acc[6]); acc[7] = fmaf(n0, HIH(v0.w), acc[7]);
  }
  float4 b0 = *(const float4*)&bias[f8 * 8];
  float4 b1 = *(const float4*)&bias[f8 * 8 + 4];
  uint4 pk;
  pk.x = pkh(fmaf(di, acc[0], b0.x), fmaf(di, acc[1], b0.y));
  pk.y = pkh(fmaf(di, acc[2], b0.z), fmaf(di, acc[3], b0.w));
  pk.z = pkh(fmaf(di, acc[4], b1.x), fmaf(di, acc[5], b1.y));
  pk.w = pkh(fmaf(di, acc[6], b1.z), fmaf(di, acc[7], b1.w));
  outv[(size_t)node * TPN + f8] = pk;
}

// ------------- heads prop (F=64) fused with reparameterization ----------
__global__ __launch_bounds__(256) void k_prop64_final(const uint4* __restrict__ T,
    const float* __restrict__ dinv, const int* __restrict__ off,
    const unsigned int* __restrict__ erec, const float* __restrict__ bias,
    const float* __restrict__ eps, float* __restrict__ out, int n) {
  constexpr int TPN = 8;
  int node = blockIdx.x * 32 + threadIdx.x / TPN;
  int f8 = threadIdx.x % TPN;
  if (node >= n) return;
  float di = dinv[node];
  float acc[8];
  {
    uint4 v = T[(size_t)node * TPN + f8];
    acc[0] = di * LOH(v.x); acc[1] = di * HIH(v.x);
    acc[2] = di * LOH(v.y); acc[3] = di * HIH(v.y);
    acc[4] = di * LOH(v.z); acc[5] = di * HIH(v.z);
    acc[6] = di * LOH(v.w); acc[7] = di * HIH(v.w);
  }
  int e = off[node], eend = off[node + 1];
  for (; e + 3 < eend; e += 4) {
    unsigned r0 = erec[e], r1 = erec[e + 1], r2 = erec[e + 2], r3 = erec[e + 3];
    uint4 v0 = T[(size_t)(r0 >> 16) * TPN + f8];
    uint4 v1 = T[(size_t)(r1 >> 16) * TPN + f8];
    uint4 v2 = T[(size_t)(r2 >> 16) * TPN + f8];
    uint4 v3 = T[(size_t)(r3 >> 16) * TPN + f8];
    float n0 = LOH(r0), n1 = LOH(r1), n2 = LOH(r2), n3 = LOH(r3);
    acc[0] = fmaf(n0, LOH(v0.x), acc[0]); acc[1] = fmaf(n0, HIH(v0.x), acc[1]);
    acc[2] = fmaf(n0, LOH(v0.y), acc[2]); acc[3] = fmaf(n0, HIH(v0.y), acc[3]);
    acc[4] = fmaf(n0, LOH(v0.z), acc[4]); acc[5] = fmaf(n0, HIH(v0.z), acc[5]);
    acc[6] = fmaf(n0, LOH(v0.w), acc[6]); acc[7] = fmaf(n0, HIH(v0.w), acc[7]);
    acc[0] = fmaf(n1, LOH(v1.x), acc[0]); acc[1] = fmaf(n1, HIH(v1.x), acc[1]);
    acc[2] = fmaf(n1, LOH(v1.y), acc[2]); acc[3] = fmaf(n1, HIH(v1.y), acc[3]);
    acc[4] = fmaf(n1, LOH(v1.z), acc[4]); acc[5] = fmaf(n1, HIH(v1.z), acc[5]);
    acc[6] = fmaf(n1, LOH(v1.w), acc[6]); acc[7] = fmaf(n1, HIH(v1.w), acc[7]);
    acc[0] = fmaf(n2, LOH(v2.x), acc[0]); acc[1] = fmaf(n2, HIH(v2.x), acc[1]);
    acc[2] = fmaf(n2, LOH(v2.y), acc[2]); acc[3] = fmaf(n2, HIH(v2.y), acc[3]);
    acc[4] = fmaf(n2, LOH(v2.z), acc[4]); acc[5] = fmaf(n2, HIH(v2.z), acc[5]);
    acc[6] = fmaf(n2, LOH(v2.w), acc[6]); acc[7] = fmaf(n2, HIH(v2.w), acc[7]);
    acc[0] = fmaf(n3, LOH(v3.x), acc[0]); acc[1] = fmaf(n3, HIH(v3.x), acc[1]);
    acc[2] = fmaf(n3, LOH(v3.y), acc[2]); acc[3] = fmaf(n3, HIH(v3.y), acc[3]);
    acc[4] = fmaf(n3, LOH(v3.z), acc[4]); acc[5] = fmaf(n3, HIH(v3.z), acc[5]);
    acc[6] = fmaf(n3, LOH(v3.w), acc[6]); acc[7] = fmaf(n3, HIH(v3.w), acc[7]);
  }
  for (; e < eend; ++e) {
    unsigned r0 = erec[e];
    uint4 v0 = T[(size_t)(r0 >> 16) * TPN + f8];
    float n0 = LOH(r0);
    acc[0] = fmaf(n0, LOH(v0.x), acc[0]); acc[1] = fmaf(n0, HIH(v0.x), acc[1]);
    acc[2] = fmaf(n0, LOH(v0.y), acc[2]); acc[3] = fmaf(n0, HIH(v0.y), acc[3]);
    acc[4] = fmaf(n0, LOH(v0.z), acc[4]); acc[5] = fmaf(n0, HIH(v0.z), acc[5]);
    acc[6] = fmaf(n0, LOH(v0.w), acc[6]); acc[7] = fmaf(n0, HIH(v0.w), acc[7]);
  }
  float4 b0 = *(const float4*)&bias[f8 * 8];
  float4 b1 = *(const float4*)&bias[f8 * 8 + 4];
  float r[8];
  r[0] = fmaf(di, acc[0], b0.x); r[1] = fmaf(di, acc[1], b0.y);
  r[2] = fmaf(di, acc[2], b0.z); r[3] = fmaf(di, acc[3], b0.w);
  r[4] = fmaf(di, acc[4], b1.x); r[5] = fmaf(di, acc[5], b1.y);
  r[6] = fmaf(di, acc[6], b1.z); r[7] = fmaf(di, acc[7], b1.w);
  float p[8];
#pragma unroll
  for (int i = 0; i < 8; ++i) p[i] = __shfl_xor(r[i], 4);
  size_t M = (size_t)n * 32;
  if (f8 < 4) {
    int jb = f8 * 8;
    float4 e0 = *(const float4*)&eps[(size_t)node * 32 + jb];
    float4 e1 = *(const float4*)&eps[(size_t)node * 32 + jb + 4];
    float ev[8] = {e0.x, e0.y, e0.z, e0.w, e1.x, e1.y, e1.z, e1.w};
    float qz[8];
#pragma unroll
    for (int i = 0; i < 8; ++i) {
      float qs = p[i];
      float sp = fmaxf(qs, 0.f) + log1pf(expf(-fabsf(qs)));
      qz[i] = fmaf(sp + 1e-6f, ev[i], r[i]);
    }
    float* oz = &out[(size_t)node * 32 + jb];
    *(float4*)oz = make_float4(qz[0], qz[1], qz[2], qz[3]);
    *(float4*)(oz + 4) = make_float4(qz[4], qz[5], qz[6], qz[7]);
    float* om = &out[M + (size_t)node * 32 + jb];
    *(float4*)om = make_float4(r[0], r[1], r[2], r[3]);
    *(float4*)(om + 4) = make_float4(r[4], r[5], r[6], r[7]);
  } else {
    int jb = (f8 - 4) * 8;
    float* os = &out[2 * M + (size_t)node * 32 + jb];
    *(float4*)os = make_float4(r[0], r[1], r[2], r[3]);
    *(float4*)(os + 4) = make_float4(r[4], r[5], r[6], r[7]);
  }
}

// ---------------- BatchNorm stats (coalesced uint4 + wave/LDS reduce) ----
__global__ __launch_bounds__(256) void k_stats(const uint4* __restrict__ X4,
    float* __restrict__ stats, int n) {
  int t = threadIdx.x;
  int chunk = t & 15;
  int sub = t >> 4;
  float s[8] = {0, 0, 0, 0, 0, 0, 0, 0};
  float s2[8] = {0, 0, 0, 0, 0, 0, 0, 0};
  for (int node = blockIdx.x * 16 + sub; node < n; node += gridDim.x * 16) {
    uint4 v = X4[(size_t)node * 16 + chunk];
    float f[8] = {LOH(v.x), HIH(v.x), LOH(v.y), HIH(v.y),
                  LOH(v.z), HIH(v.z), LOH(v.w), HIH(v.w)};
#pragma unroll
    for (int i = 0; i < 8; ++i) { s[i] += f[i]; s2[i] += f[i] * f[i]; }
  }
#pragma unroll
  for (int m = 16; m <= 32; m <<= 1) {
#pragma unroll
    for (int i = 0; i < 8; ++i) {
      s[i] += __shfl_xor(s[i], m);
      s2[i] += __shfl_xor(s2[i], m);
    }
  }
  __shared__ float red[4][16][16];
  if ((t & 48) == 0) {
    int wv = t >> 6;
#pragma unroll
    for (int i = 0; i < 8; ++i) {
      red[wv][chunk][i] = s[i];
      red[wv][chunk][8 + i] = s2[i];
    }
  }
  __syncthreads();
  int c16 = t >> 4, j = t & 15;
  float v = red[0][c16][j] + red[1][c16][j] + red[2][c16][j] + red[3][c16][j];
  int col = c16 * 8 + (j & 7);
  atomicAdd(&stats[(j < 8) ? col : 128 + col], v);
}

// ---------------- launch ----------------

extern "C" void kernel_launch(void* const* d_in, const int* in_sizes, int n_in,
                              void* d_out, int out_size, void* d_ws, size_t ws_size,
                              hipStream_t stream) {
  const float* x  = (const float*)d_in[0];
  const int*   ei = (const int*)d_in[1];
  const float* ew = (const float*)d_in[2];
  const float* W0 = (const float*)d_in[3];
  const float* b0 = (const float*)d_in[4];
  const float* W1 = (const float*)d_in[5];
  const float* b1 = (const float*)d_in[6];
  const float* g0 = (const float*)d_in[7];
  const float* be0 = (const float*)d_in[8];
  const float* g1 = (const float*)d_in[9];
  const float* be1 = (const float*)d_in[10];
  const float* Wm = (const float*)d_in[11];
  const float* bm = (const float*)d_in[12];
  const float* Ws = (const float*)d_in[13];
  const float* bs = (const float*)d_in[14];
  const float* eps = (const float*)d_in[15];
  float* out = (float*)d_out;

  const int n = in_sizes[0] / HID;
  const int E = in_sizes[1] / 2;
  const int* esrc = ei;
  const int* edst = ei + E;

  char* base = (char*)d_ws;
  size_t cur = 0;
  auto alloc = [&](size_t bytes) {
    size_t o = cur;
    cur = (cur + bytes + 255) & ~(size_t)255;
    return (void*)(base + o);
  };
  unsigned long long* packed = (unsigned long long*)alloc((size_t)n * 8);
  float* dinv  = (float*)alloc((size_t)n * 4);
  int*   cnt   = (int*)alloc((size_t)n * 4);
  int*   coff  = (int*)alloc((size_t)(n + 1) * 4);
  unsigned short* rank = (unsigned short*)alloc((size_t)E * 2);
  unsigned int* erec = (unsigned int*)alloc((size_t)E * 4);
  int*   bsum  = (int*)alloc(64 * 4);
  float* stats0 = (float*)alloc(256 * 4);
  float* stats1 = (float*)alloc(256 * 4);
  float* bcat  = (float*)alloc(64 * 4);
  uint4* Wsw0  = (uint4*)alloc(8 * 4 * 64 * 16);
  uint4* Wsw1  = (uint4*)alloc(8 * 4 * 64 * 16);
  uint4* Wswc  = (uint4*)alloc(4 * 4 * 64 * 16);
  unsigned short* bufA = (unsigned short*)alloc((size_t)n * 128 * 2);  // fp16
  unsigned short* bufB = (unsigned short*)alloc((size_t)n * 128 * 2);  // fp16
  unsigned short* bufC = (unsigned short*)alloc((size_t)n * 128 * 2);  // fp16 residual
  (void)ws_size;

  const int eb4 = (E + 1023) / 1024;
  const int gemmb = (n + BM - 1) / BM;
  const int scb = (n + SCH - 1) / SCH;
  const int prepb = 21 + (n + 255) / 256;

  // --- prep: W swizzles + zero packed/stats, one launch ---
  k_prep<<<prepb, 256, 0, stream>>>(W0, W1, Wm, Ws, bm, bs, Wsw0, Wsw1, Wswc,
                                    bcat, packed, stats0, stats1, n);

  // --- fused: layer-0 GEMM (first) || edge-degree atomics (4/thread) ---
  k_front<<<gemmb + eb4, 256, 0, stream>>>(edst, ew, packed, rank, E, gemmb,
                                           x, Wsw0, bufA, n);

  // --- CSR ---
  k_dinv_scan<<<scb, 256, 0, stream>>>(packed, dinv, cnt, bsum, n);
  k_scan_out<<<scb, 256, 0, stream>>>(cnt, bsum, coff, scb, n);
  k_fill<<<eb4, 256, 0, stream>>>(esrc, edst, ew, dinv, coff, rank, erec, E);

  // --- layer 0 prop + stats ---
  k_propb128<<<(n + 15) / 16, 256, 0, stream>>>((const uint4*)bufA, dinv, coff,
                                                erec, b0, (uint4*)bufB, n);
  k_stats<<<128, 256, 0, stream>>>((const uint4*)bufB, stats0, n);

  // --- layer 1 (BN0+relu in gemm staging; residual h0 -> bufC fp16) ---
  k_gemm<128, 1><<<gemmb, 256, 0, stream>>>(bufB, Wsw1, bufA, n, stats0, g0, be0,
                                            nullptr, (uint4*)bufC);
  k_propb128<<<(n + 15) / 16, 256, 0, stream>>>((const uint4*)bufA, dinv, coff,
                                                erec, b1, (uint4*)bufB, n);
  k_stats<<<128, 256, 0, stream>>>((const uint4*)bufB, stats1, n);

  // --- heads (BN1+relu+residual in gemm staging; mean||logstd) ---
  k_gemm<64, 2><<<gemmb, 256, 0, stream>>>(bufB, Wswc, bufA, n, stats1, g1, be1,
                                           (const uint4*)bufC, nullptr);
  k_prop64_final<<<(n + 31) / 32, 256, 0, stream>>>((const uint4*)bufA, dinv,
                                                    coff, erec, bcat, eps, out, n);
}